// Round 17
// baseline (236.040 us; speedup 1.0000x reference)
//
#include <hip/hip_runtime.h>

typedef unsigned short u16;
typedef unsigned int   u32;
typedef __bf16  bf16x8 __attribute__((ext_vector_type(8)));
typedef float   f32x4  __attribute__((ext_vector_type(4)));
typedef float   f32x16 __attribute__((ext_vector_type(16)));
typedef u16     u16x4  __attribute__((ext_vector_type(4)));
typedef u16     u16x8  __attribute__((ext_vector_type(8)));
typedef u32     u32x4  __attribute__((ext_vector_type(4)));

#define S_LEN 2048
#define NH 32
#define NKVH 8
#define HD 128
#define QKVST 6144          /* packed QKV row stride  */
#define AOST  4096          /* attn-out row stride    */
#define ATT_SCALE 0.08838834764831845f
#define LOG2E 1.4426950408889634f
#define QSC2 (ATT_SCALE * LOG2E)
#define RESCALE_THR2 11.5f
#define PARTSZ 16640        /* u16 per partial: 128x128 bf16 O + 128 f32 lse */

__device__ __forceinline__ u16 f2bf(float f){
  u32 u = __builtin_bit_cast(u32, f);
  u += 0x7FFFu + ((u >> 16) & 1u);
  return (u16)(u >> 16);
}
__device__ __forceinline__ float bf2f(u16 h){
  u32 u = ((u32)h) << 16;
  return __builtin_bit_cast(float, u);
}
__device__ __forceinline__ u32 cvtpk(float lo, float hi){
  u32 d;
  asm("v_cvt_pk_bf16_f32 %0, %1, %2" : "=v"(d) : "v"(lo), "v"(hi));
  return d;
}
// async global->LDS, 16B per lane. Dest must be wave-uniform base + lane*16.
__device__ __forceinline__ void gload_lds16(const u16* g, u16* l){
  __builtin_amdgcn_global_load_lds(
      (const __attribute__((address_space(1))) void*)g,
      (__attribute__((address_space(3))) void*)l, 16, 0, 0);
}

// ------------- fused f32 -> bf16 convert of ALL inputs (one launch) --------
__global__ void cvt_all_kernel(const f32x4* __restrict__ hs, const f32x4* __restrict__ wq,
                               const f32x4* __restrict__ wk, const f32x4* __restrict__ wv,
                               const f32x4* __restrict__ wo, u16x4* __restrict__ out){
  int i = blockIdx.x * 256 + threadIdx.x;          // 0 .. 6291455
  const f32x4* src; int off;
  if      (i < 1048576){ src = hs; off = i; }
  else if (i < 3145728){ src = wq; off = i - 1048576; }
  else if (i < 3670016){ src = wk; off = i - 3145728; }
  else if (i < 4194304){ src = wv; off = i - 3670016; }
  else                 { src = wo; off = i - 4194304; }
  f32x4 v = src[off];
  u16x4 o;
  o[0] = f2bf(v[0]); o[1] = f2bf(v[1]); o[2] = f2bf(v[2]); o[3] = f2bf(v[3]);
  out[i] = o;
}

// ---------------- GEMM: C[M][N] = X[M][K] @ W[N][K]^T (bf16 in, f32 acc) ----
// BMxBN tile, BK sub-tiles, dbuf prefetch. QKV: 128/128/32 (m97 geometry,
// 32KB LDS, 3 blocks/CU, grid 768 = one exact round). O-proj: 128/64/32
// (24KB LDS -> deeper co-residency; BK=64's 48KB capped at 3/CU).
template<int OUT_BF16, int ROPE, int BM, int BN, int BK>
__global__ __launch_bounds__(256, 2)
void gemm_bt_kernel(const u16* __restrict__ X, const u16* __restrict__ W,
                    void* __restrict__ Cv, int M, int N, int K,
                    const float* __restrict__ cosv, const float* __restrict__ sinv){
  const int NS = BK / 32;
  __shared__ __align__(16) u16 As[2][NS][BM * 32];
  __shared__ __align__(16) u16 Bs[2][NS][BN * 32];
  const int MI = BM / 32, NJ = BN / 32;
  const int m0 = blockIdx.y * BM, n0 = blockIdx.x * BN;
  const int tid = threadIdx.x;
  const int wave = tid >> 6, lane = tid & 63;
  const int wm = wave >> 1, wn = wave & 1;
  const int g = lane >> 4, ln = lane & 15;
  const int r0 = tid >> 2;
  const int cc = (tid & 3) * 8;
  f32x4 acc[MI][NJ] = {};
  const u16* xa0 = X + (size_t)(m0 + r0) * K + cc;
  const u16* xa1 = X + (size_t)(m0 + r0 + 64) * K + cc;
  const u16* wb0 = W + (size_t)(n0 + r0) * K + cc;
  const u16* wb1 = W + (size_t)(n0 + r0 + 64) * K + cc;

  auto stage = [&](int buf, int k0){
    #pragma unroll
    for (int s = 0; s < NS; s++){
      const int kc = k0 + s * 32;
      gload_lds16(xa0 + kc, &As[buf][s][tid * 8]);
      if (BM == 128) gload_lds16(xa1 + kc, &As[buf][s][2048 + tid * 8]);
      gload_lds16(wb0 + kc, &Bs[buf][s][tid * 8]);
      if (BN == 128) gload_lds16(wb1 + kc, &Bs[buf][s][2048 + tid * 8]);
    }
  };

  stage(0, 0);
  __syncthreads();
  int cur = 0;
  for (int k0 = 0; k0 < K; k0 += BK){
    if (k0 + BK < K) stage(cur ^ 1, k0 + BK);
    #pragma unroll
    for (int s = 0; s < NS; s++){
      bf16x8 a[MI], b[NJ];
      #pragma unroll
      for (int f = 0; f < MI; f++) a[f] = *(const bf16x8*)&As[cur][s][(wm * (BM / 2) + f * 16 + ln) * 32 + g * 8];
      #pragma unroll
      for (int f = 0; f < NJ; f++) b[f] = *(const bf16x8*)&Bs[cur][s][(wn * (BN / 2) + f * 16 + ln) * 32 + g * 8];
      __builtin_amdgcn_s_setprio(1);
      #pragma unroll
      for (int i = 0; i < MI; i++)
        #pragma unroll
        for (int j = 0; j < NJ; j++)
          acc[i][j] = __builtin_amdgcn_mfma_f32_16x16x32_bf16(a[i], b[j], acc[i][j], 0, 0, 0);
      __builtin_amdgcn_s_setprio(0);
    }
    __syncthreads();
    cur ^= 1;
  }
  if (ROPE && BN == 128){
    if (wn == 0 && n0 < 5120){
      #pragma unroll
      for (int i = 0; i < MI; i++)
        #pragma unroll
        for (int r = 0; r < 4; r++){
          const int row = m0 + wm * (BM / 2) + i * 16 + g * 4 + r;
          #pragma unroll
          for (int j = 0; j < 2; j++){
            const int d = j * 16 + ln;
            float c  = cosv[row * 64 + d];
            float sn = sinv[row * 64 + d];
            float x0 = acc[i][j][r], x1 = acc[i][j + 2][r];
            acc[i][j][r]     = x0 * c - x1 * sn;
            acc[i][j + 2][r] = x1 * c + x0 * sn;
          }
        }
    }
    if (n0 < 4096){
      #pragma unroll
      for (int i = 0; i < MI; i++)
        #pragma unroll
        for (int j = 0; j < NJ; j++)
          #pragma unroll
          for (int r = 0; r < 4; r++) acc[i][j][r] *= QSC2;
    }
  }
  #pragma unroll
  for (int i = 0; i < MI; i++)
    #pragma unroll
    for (int j = 0; j < NJ; j++)
      #pragma unroll
      for (int r = 0; r < 4; r++){
        int row = m0 + wm * (BM / 2) + i * 16 + g * 4 + r;
        int col = n0 + wn * (BN / 2) + j * 16 + ln;
        if (OUT_BF16) ((u16*)Cv)[(size_t)row * N + col] = f2bf(acc[i][j][r]);
        else          ((float*)Cv)[(size_t)row * N + col] = acc[i][j][r];
      }
}

// ---------------- V transpose: VT[kvh][vd][s] from packed QKV -------------
__global__ void vtrans_kernel(const u16* __restrict__ QKV, u16* __restrict__ VT){
  int idx = blockIdx.x * 256 + threadIdx.x;
  if (idx >= NKVH * HD * S_LEN) return;
  int s   = idx & (S_LEN - 1);
  int vd  = (idx >> 11) & (HD - 1);
  int kvh = idx >> 18;
  VT[idx] = QKV[(size_t)s * QKVST + 5120 + kvh * HD + vd];
}

// ---------------- causal flash attention, stream-K split (uniform 17) ------
// R16 structure (verified): 512 uniform-17-tile blocks, role A (b<256) =
// long stripe tiles [0,17) -> partial; role B = long stripe [17,32-2p) ->
// partial, then short stripe p (2p+2 tiles) -> final. NEW vs R16: role B
// prefetches phase-2 tile 0 into the spare dbuf slot during phase-1's last
// tile; the mid-block epilogue's transpose arena moves to the two DEAD
// buffer halves (Ks[cur^1] + Vs[cur^1], wave-split) so the prefetch
// survives -> one fewer unhidden cold stage per role-B block.
__global__ __launch_bounds__(256, 2)
void attn_kernel(const u16* __restrict__ QKV, const u16* __restrict__ VT,
                 const float* __restrict__ sinkb, u16* __restrict__ AO,
                 u16* __restrict__ PART){
  __shared__ __align__(16) u16 Ks[2][32 * 256];   // 64 keys: key-pair rows, 512B
  __shared__ __align__(16) u16 Vs[2][32 * 256];   // 128 vd: vd-quad rows, 512B
  const int b    = blockIdx.x;
  const int kvh  = b & 7;                  // XCD-aligned kv-head
  const int head = kvh * 4 + ((b >> 3) & 3);
  const int p    = (b >> 5) & 7;           // pair index 0..7
  const int role = b >> 8;                 // 0 = A, 1 = B
  const int qtL  = 15 - p;
  const int tid  = threadIdx.x;
  const int w    = tid >> 6;
  const int lane = tid & 63;
  const int l31  = lane & 31, hi = lane >> 5;

  const u16* Kbase = QKV + 4096 + kvh * HD;           // + row*QKVST
  const u16* Vbase = VT + (size_t)kvh * HD * S_LEN;   // + vd*S_LEN + key

  auto stage = [&](int buf, int kt){
    const int k0 = kt * 64;
    #pragma unroll
    for (int pp = 0; pp < 4; pp++){
      int idx = pp * 256 + tid;
      int r = idx >> 5, c = idx & 31;
      int cs = c ^ r;
      int key = r * 2 + (cs >> 4), d8 = (cs & 15) * 8;
      gload_lds16(Kbase + (size_t)(k0 + key) * QKVST + d8, &Ks[buf][idx * 8]);
    }
    #pragma unroll
    for (int pp = 0; pp < 4; pp++){
      int idx = pp * 256 + tid;
      int r = idx >> 5, c = idx & 31;
      int cs = c ^ r;
      int vd = r * 4 + (cs >> 3), k8 = (cs & 7) * 8;
      gload_lds16(Vbase + (size_t)vd * S_LEN + k0 + k8, &Vs[buf][idx * 8]);
    }
  };

  const float sb2 = sinkb[head] * LOG2E;
  bf16x8 qB[8];
  float m, Ll;
  f32x16 O[4];

  auto load_q = [&](int q0){
    const int qw = q0 + w * 32;
    const u16* qrow = QKV + (size_t)(qw + l31) * QKVST + head * HD;
    #pragma unroll
    for (int t = 0; t < 8; t++) qB[t] = *(const bf16x8*)(qrow + t * 16 + hi * 8);
    #pragma unroll
    for (int n = 0; n < 4; n++) O[n] = f32x16{};
  };

  auto do_tile = [&](int cur, int k0, int qw){
    const u16* Kc = Ks[cur];
    const u16* Vc = Vs[cur];
    f32x16 sc0 = {}, sc1 = {};
    const int krow0 = (l31 >> 1);
    const int kc0   = ((l31 & 1) << 4) | hi;
    __builtin_amdgcn_s_setprio(1);
    #pragma unroll
    for (int t = 0; t < 8; t++){
      bf16x8 ka0 = *(const bf16x8*)&Kc[krow0 * 256 + ((kc0 + 2 * t) ^ krow0) * 8];
      bf16x8 ka1 = *(const bf16x8*)&Kc[(16 + krow0) * 256 + ((kc0 + 2 * t) ^ (16 + krow0)) * 8];
      sc0 = __builtin_amdgcn_mfma_f32_32x32x16_bf16(ka0, qB[t], sc0, 0, 0, 0);
      sc1 = __builtin_amdgcn_mfma_f32_32x32x16_bf16(ka1, qB[t], sc1, 0, 0, 0);
    }
    __builtin_amdgcn_s_setprio(0);

    if (k0 + 63 > qw){
      const int qg = qw + l31;
      #pragma unroll
      for (int r = 0; r < 16; r++){
        int keyr = k0 + (r & 3) + 8 * (r >> 2) + 4 * hi;
        if (keyr      > qg) sc0[r] = -1e30f;
        if (keyr + 32 > qg) sc1[r] = -1e30f;
      }
    }
    float mx = sc0[0];
    #pragma unroll
    for (int r = 1; r < 16; r++) mx = fmaxf(mx, sc0[r]);
    #pragma unroll
    for (int r = 0; r < 16; r++) mx = fmaxf(mx, sc1[r]);
    mx = fmaxf(mx, __shfl_xor(mx, 32));
    if (!__all(mx <= m + RESCALE_THR2)){
      float mn = fmaxf(m, mx);
      float sf = exp2f(m - mn);
      m = mn;
      #pragma unroll
      for (int n = 0; n < 4; n++)
        #pragma unroll
        for (int r = 0; r < 16; r++) O[n][r] *= sf;
      Ll *= sf;
    }
    float p0[16], p1[16];
    #pragma unroll
    for (int r = 0; r < 16; r++){ p0[r] = exp2f(sc0[r] - m); Ll += p0[r]; }
    #pragma unroll
    for (int r = 0; r < 16; r++){ p1[r] = exp2f(sc1[r] - m); Ll += p1[r]; }

    __builtin_amdgcn_s_setprio(1);
    #pragma unroll
    for (int c = 0; c < 4; c++){
      const float* ps = (c & 2) ? p1 : p0;
      const int bb = (c & 1) * 8;
      u32 wa = cvtpk(ps[bb + 0], ps[bb + 1]);
      u32 wb = cvtpk(ps[bb + 2], ps[bb + 3]);
      u32 wc = cvtpk(ps[bb + 4], ps[bb + 5]);
      u32 wd = cvtpk(ps[bb + 6], ps[bb + 7]);
      asm("v_permlane32_swap_b32 %0, %1" : "+v"(wa), "+v"(wc));
      asm("v_permlane32_swap_b32 %0, %1" : "+v"(wb), "+v"(wd));
      u32x4 wv_; wv_[0] = wa; wv_[1] = wb; wv_[2] = wc; wv_[3] = wd;
      bf16x8 pf = __builtin_bit_cast(bf16x8, wv_);
      #pragma unroll
      for (int n = 0; n < 4; n++){
        const int vrow = n * 8 + (l31 >> 2);
        const int vcc  = ((l31 & 3) << 3) | (c << 1) | hi;
        bf16x8 va = *(const bf16x8*)&Vc[vrow * 256 + (vcc ^ vrow) * 8];
        O[n] = __builtin_amdgcn_mfma_f32_32x32x16_bf16(va, pf, O[n], 0, 0, 0);
      }
    }
    __builtin_amdgcn_s_setprio(0);
  };

  // epilogue: transpose O via a 32KB arena given as two 16KB halves
  // (arlo = rows 0..63, arhi = rows 64..127); final -> AO, else -> PART+lse
  auto epilogue = [&](int q0, bool final_, int rr_, u16* arlo, u16* arhi){
    float l = Ll + __shfl_xor(Ll, 32);
    float inv, lse;
    if (l > 0.f){ inv = 1.f / l; lse = m + __log2f(l); }
    else        { inv = 0.f;     lse = -1e30f; }
    u16* ap = (w < 2) ? arlo + (w * 32 + l31) * 128
                      : arhi + ((w - 2) * 32 + l31) * 128;
    #pragma unroll
    for (int n = 0; n < 4; n++)
      #pragma unroll
      for (int r = 0; r < 16; r++){
        int vd = n * 32 + (r & 3) + 8 * (r >> 2) + 4 * hi;
        int ch = (vd >> 3) ^ (l31 & 15);
        ap[ch * 8 + (vd & 7)] = f2bf(O[n][r] * inv);
      }
    __syncthreads();
    #pragma unroll
    for (int pp = 0; pp < 8; pp++){
      int idx = pp * 256 + tid;
      int row = idx >> 4, c = idx & 15;
      const u16* rp = (row < 64) ? arlo + row * 128 : arhi + (row - 64) * 128;
      u16x8 v = *(const u16x8*)&rp[(c ^ (row & 15)) * 8];
      if (final_){
        *(u16x8*)&AO[(size_t)(q0 + row) * AOST + head * HD + c * 8] = v;
      } else {
        u16* base = PART + (size_t)((head * 8 + p) * 2 + rr_) * PARTSZ;
        *(u16x8*)&base[row * 128 + c * 8] = v;
      }
    }
    if (!final_ && hi == 0){
      u16* base = PART + (size_t)((head * 8 + p) * 2 + rr_) * PARTSZ;
      ((float*)(base + 16384))[w * 32 + l31] = lse;
    }
    __syncthreads();                       // arena reads done before next stage
  };

  const int q0L = qtL * 128;
  if (role == 0){
    // role A: long stripe, tiles [0, 17), sink in init
    load_q(q0L);
    m = sb2; Ll = (hi == 0) ? 1.f : 0.f;
    const int qw = q0L + w * 32;
    stage(0, 0);
    __syncthreads();
    int cur = 0;
    for (int kt = 0; kt < 17; kt++){
      if (kt + 1 < 17) stage(cur ^ 1, kt + 1);
      if (kt * 64 < qw + 32) do_tile(cur, kt * 64, qw);
      __syncthreads();
      cur ^= 1;
    }
    epilogue(q0L, false, 0, &Ks[0][0], &Ks[1][0]);
  } else {
    // role B phase 1: long stripe, tiles [17, 32-2p), no sink;
    // SEAM: last iteration prefetches phase-2 tile 0 into the spare buffer.
    load_q(q0L);
    m = -3.0e38f; Ll = 0.f;
    const int qw = q0L + w * 32;
    const int kt1 = 32 - 2 * p;            // >= 18, so loop runs >= 1 iter
    stage(0, 17);
    __syncthreads();
    int cur = 0;
    for (int kt = 17; kt < kt1; kt++){
      if (kt + 1 < kt1) stage(cur ^ 1, kt + 1);
      else              stage(cur ^ 1, 0);            // phase-2 tile 0
      if (kt * 64 < qw + 32) do_tile(cur, kt * 64, qw);
      __syncthreads();
      cur ^= 1;
    }
    // cur now holds phase-2 tile 0; arena = the DEAD pair (cur^1)
    epilogue(q0L, false, 1, &Ks[cur ^ 1][0], &Vs[cur ^ 1][0]);
    // role B phase 2: short stripe p, tiles [0, 2p+2), sink in init
    const int q0S = p * 128;
    const int qwS = q0S + w * 32;
    load_q(q0S);
    m = sb2; Ll = (hi == 0) ? 1.f : 0.f;
    const int kt2 = 2 * p + 2;
    for (int kt = 0; kt < kt2; kt++){
      if (kt + 1 < kt2) stage(cur ^ 1, kt + 1);
      if (kt * 64 < qwS + 32) do_tile(cur, kt * 64, qwS);
      __syncthreads();
      cur ^= 1;
    }
    epilogue(q0S, true, 0, &Ks[0][0], &Ks[1][0]);
  }
}

// ---------------- merge partials: AO[long stripe] = lse-weighted combine ---
__global__ void merge_kernel(const u16* __restrict__ PART, u16* __restrict__ AO){
  const int sidx = blockIdx.x;             // head*8 + p
  const int h = sidx >> 3, p = sidx & 7;
  const int q0 = (15 - p) * 128;
  const u16* A = PART + (size_t)(sidx * 2 + 0) * PARTSZ;
  const u16* B = PART + (size_t)(sidx * 2 + 1) * PARTSZ;
  const float* lseA = (const float*)(A + 16384);
  const float* lseB = (const float*)(B + 16384);
  #pragma unroll
  for (int it = 0; it < 8; it++){
    int idx = it * 256 + threadIdx.x;      // 2048 chunks: row(128) x c(16)
    int row = idx >> 4, c = (idx & 15) * 8;
    float la = lseA[row], lb = lseB[row];
    float mx = fmaxf(la, lb);
    float wa = exp2f(la - mx), wb = exp2f(lb - mx);
    float inv = 1.f / (wa + wb);
    u16x8 va = *(const u16x8*)&A[row * 128 + c];
    u16x8 vb = *(const u16x8*)&B[row * 128 + c];
    u16x8 o;
    #pragma unroll
    for (int j = 0; j < 8; j++)
      o[j] = f2bf((bf2f(va[j]) * wa + bf2f(vb[j]) * wb) * inv);
    *(u16x8*)&AO[(size_t)(q0 + row) * AOST + h * HD + c] = o;
  }
}

// ---------------- host-side launch ----------------
extern "C" void kernel_launch(void* const* d_in, const int* in_sizes, int n_in,
                              void* d_out, int out_size, void* d_ws, size_t ws_size,
                              hipStream_t stream){
  (void)in_sizes; (void)n_in; (void)out_size; (void)ws_size;
  const float* hs    = (const float*)d_in[0];
  const float* cosv  = (const float*)d_in[1];
  const float* sinv  = (const float*)d_in[2];
  /* d_in[3] attention_mask: pure causal triu(NEG,1) - implemented directly */
  const float* Wq    = (const float*)d_in[4];
  const float* Wk    = (const float*)d_in[5];
  const float* Wv    = (const float*)d_in[6];
  const float* Wo    = (const float*)d_in[7];
  const float* sinkb = (const float*)d_in[8];
  float* out = (float*)d_out;

  char* ws = (char*)d_ws;
  u16* XB    = (u16*)(ws);                  //  8,388,608  X bf16 [2048][2048]
  u16* WQKVB = (u16*)(ws + 8388608);        // 25,165,824  Wqkv bf16 [6144][2048]
  u16* WOB   = (u16*)(ws + 33554432);       // 16,777,216  Wo bf16 [2048][4096]
  u16* QKV   = (u16*)(ws + 50331648);       // 25,165,824  QKV bf16 [2048][6144]
  u16* VT    = (u16*)(ws + 75497472);       //  4,194,304  V^T bf16 [8][128][2048]
  u16* AO    = (u16*)(ws + 79691776);       // 16,777,216  attn out bf16 [2048][4096]
  u16* PART  = (u16*)(ws);                  // 17,039,360  partials (XB region,
                                            //   dead after the QKV GEMM)

  cvt_all_kernel<<<24576, 256, 0, stream>>>((const f32x4*)hs, (const f32x4*)Wq,
                                            (const f32x4*)Wk, (const f32x4*)Wv,
                                            (const f32x4*)Wo, (u16x4*)ws);

  // fused QKV projection + RoPE + Q-scale(log2e): m97 geometry (128/128/32)
  gemm_bt_kernel<1, 1, 128, 128, 32><<<dim3(48, 16), 256, 0, stream>>>(XB, WQKVB, QKV, 2048, 6144, 2048, cosv, sinv);

  vtrans_kernel<<<8192, 256, 0, stream>>>(QKV, VT);

  // attention: 512 uniform-17-tile blocks (role A: b<256, role B: b>=256)
  attn_kernel<<<dim3(512), 256, 0, stream>>>(QKV, VT, sinkb, AO, PART);

  // merge split (long) stripes: 256 stripes, lse-weighted combine
  merge_kernel<<<dim3(256), 256, 0, stream>>>(PART, AO);

  // output projection (f32 out): 128/64/32 -> 24KB LDS, deeper co-residency
  gemm_bt_kernel<0, 0, 128, 64, 32><<<dim3(32, 16), 256, 0, stream>>>(AO, WOB, out, 2048, 2048, 4096, nullptr, nullptr);
}

// Round 18
// 224.762 us; speedup vs baseline: 1.0502x; 1.0502x over previous
//
#include <hip/hip_runtime.h>

typedef unsigned short u16;
typedef unsigned int   u32;
typedef __bf16  bf16x8 __attribute__((ext_vector_type(8)));
typedef float   f32x4  __attribute__((ext_vector_type(4)));
typedef float   f32x16 __attribute__((ext_vector_type(16)));
typedef u16     u16x4  __attribute__((ext_vector_type(4)));
typedef u16     u16x8  __attribute__((ext_vector_type(8)));
typedef u32     u32x4  __attribute__((ext_vector_type(4)));

#define S_LEN 2048
#define NH 32
#define NKVH 8
#define HD 128
#define QKVST 6144          /* packed QKV row stride  */
#define AOST  4096          /* attn-out row stride    */
#define ATT_SCALE 0.08838834764831845f
#define LOG2E 1.4426950408889634f
#define QSC2 (ATT_SCALE * LOG2E)
#define RESCALE_THR2 11.5f
#define PARTSZ 16640        /* u16 per partial: 128x128 bf16 O + 128 f32 lse */

__device__ __forceinline__ u16 f2bf(float f){
  u32 u = __builtin_bit_cast(u32, f);
  u += 0x7FFFu + ((u >> 16) & 1u);
  return (u16)(u >> 16);
}
__device__ __forceinline__ float bf2f(u16 h){
  u32 u = ((u32)h) << 16;
  return __builtin_bit_cast(float, u);
}
__device__ __forceinline__ u32 cvtpk(float lo, float hi){
  u32 d;
  asm("v_cvt_pk_bf16_f32 %0, %1, %2" : "=v"(d) : "v"(lo), "v"(hi));
  return d;
}
// async global->LDS, 16B per lane. Dest must be wave-uniform base + lane*16.
__device__ __forceinline__ void gload_lds16(const u16* g, u16* l){
  __builtin_amdgcn_global_load_lds(
      (const __attribute__((address_space(1))) void*)g,
      (__attribute__((address_space(3))) void*)l, 16, 0, 0);
}

// ------------- fused f32 -> bf16 convert of ALL inputs (one launch) --------
__global__ void cvt_all_kernel(const f32x4* __restrict__ hs, const f32x4* __restrict__ wq,
                               const f32x4* __restrict__ wk, const f32x4* __restrict__ wv,
                               const f32x4* __restrict__ wo, u16x4* __restrict__ out){
  int i = blockIdx.x * 256 + threadIdx.x;          // 0 .. 6291455
  const f32x4* src; int off;
  if      (i < 1048576){ src = hs; off = i; }
  else if (i < 3145728){ src = wq; off = i - 1048576; }
  else if (i < 3670016){ src = wk; off = i - 3145728; }
  else if (i < 4194304){ src = wv; off = i - 3670016; }
  else                 { src = wo; off = i - 4194304; }
  f32x4 v = src[off];
  u16x4 o;
  o[0] = f2bf(v[0]); o[1] = f2bf(v[1]); o[2] = f2bf(v[2]); o[3] = f2bf(v[3]);
  out[i] = o;
}

// ---------------- GEMM: C[M][N] = X[M][K] @ W[N][K]^T (bf16 in, f32 acc) ----
// BMxBN tile, BK sub-tiles, dbuf prefetch. QKV: 128/128/32 (m97 geometry,
// 32KB LDS, 3 blocks/CU, 16 MFMA/barrier). O-proj: 128/64/64 (48KB LDS,
// 16 MFMA/barrier). [R17 lesson: BK=32 at NJ=2 -> 8 MFMA/barrier + 2x
// barriers = drain-dominated, 58->78us. Keep >=16 MFMA per barrier.]
template<int OUT_BF16, int ROPE, int BM, int BN, int BK>
__global__ __launch_bounds__(256, 2)
void gemm_bt_kernel(const u16* __restrict__ X, const u16* __restrict__ W,
                    void* __restrict__ Cv, int M, int N, int K,
                    const float* __restrict__ cosv, const float* __restrict__ sinv){
  const int NS = BK / 32;
  __shared__ __align__(16) u16 As[2][NS][BM * 32];
  __shared__ __align__(16) u16 Bs[2][NS][BN * 32];
  const int MI = BM / 32, NJ = BN / 32;
  const int m0 = blockIdx.y * BM, n0 = blockIdx.x * BN;
  const int tid = threadIdx.x;
  const int wave = tid >> 6, lane = tid & 63;
  const int wm = wave >> 1, wn = wave & 1;
  const int g = lane >> 4, ln = lane & 15;
  const int r0 = tid >> 2;
  const int cc = (tid & 3) * 8;
  f32x4 acc[MI][NJ] = {};
  const u16* xa0 = X + (size_t)(m0 + r0) * K + cc;
  const u16* xa1 = X + (size_t)(m0 + r0 + 64) * K + cc;
  const u16* wb0 = W + (size_t)(n0 + r0) * K + cc;
  const u16* wb1 = W + (size_t)(n0 + r0 + 64) * K + cc;

  auto stage = [&](int buf, int k0){
    #pragma unroll
    for (int s = 0; s < NS; s++){
      const int kc = k0 + s * 32;
      gload_lds16(xa0 + kc, &As[buf][s][tid * 8]);
      if (BM == 128) gload_lds16(xa1 + kc, &As[buf][s][2048 + tid * 8]);
      gload_lds16(wb0 + kc, &Bs[buf][s][tid * 8]);
      if (BN == 128) gload_lds16(wb1 + kc, &Bs[buf][s][2048 + tid * 8]);
    }
  };

  stage(0, 0);
  __syncthreads();
  int cur = 0;
  for (int k0 = 0; k0 < K; k0 += BK){
    if (k0 + BK < K) stage(cur ^ 1, k0 + BK);
    #pragma unroll
    for (int s = 0; s < NS; s++){
      bf16x8 a[MI], b[NJ];
      #pragma unroll
      for (int f = 0; f < MI; f++) a[f] = *(const bf16x8*)&As[cur][s][(wm * (BM / 2) + f * 16 + ln) * 32 + g * 8];
      #pragma unroll
      for (int f = 0; f < NJ; f++) b[f] = *(const bf16x8*)&Bs[cur][s][(wn * (BN / 2) + f * 16 + ln) * 32 + g * 8];
      __builtin_amdgcn_s_setprio(1);
      #pragma unroll
      for (int i = 0; i < MI; i++)
        #pragma unroll
        for (int j = 0; j < NJ; j++)
          acc[i][j] = __builtin_amdgcn_mfma_f32_16x16x32_bf16(a[i], b[j], acc[i][j], 0, 0, 0);
      __builtin_amdgcn_s_setprio(0);
    }
    __syncthreads();
    cur ^= 1;
  }
  if (ROPE && BN == 128){
    if (wn == 0 && n0 < 5120){
      #pragma unroll
      for (int i = 0; i < MI; i++)
        #pragma unroll
        for (int r = 0; r < 4; r++){
          const int row = m0 + wm * (BM / 2) + i * 16 + g * 4 + r;
          #pragma unroll
          for (int j = 0; j < 2; j++){
            const int d = j * 16 + ln;
            float c  = cosv[row * 64 + d];
            float sn = sinv[row * 64 + d];
            float x0 = acc[i][j][r], x1 = acc[i][j + 2][r];
            acc[i][j][r]     = x0 * c - x1 * sn;
            acc[i][j + 2][r] = x1 * c + x0 * sn;
          }
        }
    }
    if (n0 < 4096){
      #pragma unroll
      for (int i = 0; i < MI; i++)
        #pragma unroll
        for (int j = 0; j < NJ; j++)
          #pragma unroll
          for (int r = 0; r < 4; r++) acc[i][j][r] *= QSC2;
    }
  }
  #pragma unroll
  for (int i = 0; i < MI; i++)
    #pragma unroll
    for (int j = 0; j < NJ; j++)
      #pragma unroll
      for (int r = 0; r < 4; r++){
        int row = m0 + wm * (BM / 2) + i * 16 + g * 4 + r;
        int col = n0 + wn * (BN / 2) + j * 16 + ln;
        if (OUT_BF16) ((u16*)Cv)[(size_t)row * N + col] = f2bf(acc[i][j][r]);
        else          ((float*)Cv)[(size_t)row * N + col] = acc[i][j][r];
      }
}

// ---------------- V transpose: VT[kvh][vd][s] from packed QKV -------------
__global__ void vtrans_kernel(const u16* __restrict__ QKV, u16* __restrict__ VT){
  int idx = blockIdx.x * 256 + threadIdx.x;
  if (idx >= NKVH * HD * S_LEN) return;
  int s   = idx & (S_LEN - 1);
  int vd  = (idx >> 11) & (HD - 1);
  int kvh = idx >> 18;
  VT[idx] = QKV[(size_t)s * QKVST + 5120 + kvh * HD + vd];
}

// ---------------- causal flash attention, stream-K split (uniform 17) ------
// (unchanged from R17: 512 uniform-17-tile blocks, role A/B with lse-merge,
// role-B seam prefetch into spare dbuf slot, epilogue arena = dead halves)
__global__ __launch_bounds__(256, 2)
void attn_kernel(const u16* __restrict__ QKV, const u16* __restrict__ VT,
                 const float* __restrict__ sinkb, u16* __restrict__ AO,
                 u16* __restrict__ PART){
  __shared__ __align__(16) u16 Ks[2][32 * 256];   // 64 keys: key-pair rows, 512B
  __shared__ __align__(16) u16 Vs[2][32 * 256];   // 128 vd: vd-quad rows, 512B
  const int b    = blockIdx.x;
  const int kvh  = b & 7;                  // XCD-aligned kv-head
  const int head = kvh * 4 + ((b >> 3) & 3);
  const int p    = (b >> 5) & 7;           // pair index 0..7
  const int role = b >> 8;                 // 0 = A, 1 = B
  const int qtL  = 15 - p;
  const int tid  = threadIdx.x;
  const int w    = tid >> 6;
  const int lane = tid & 63;
  const int l31  = lane & 31, hi = lane >> 5;

  const u16* Kbase = QKV + 4096 + kvh * HD;           // + row*QKVST
  const u16* Vbase = VT + (size_t)kvh * HD * S_LEN;   // + vd*S_LEN + key

  auto stage = [&](int buf, int kt){
    const int k0 = kt * 64;
    #pragma unroll
    for (int pp = 0; pp < 4; pp++){
      int idx = pp * 256 + tid;
      int r = idx >> 5, c = idx & 31;
      int cs = c ^ r;
      int key = r * 2 + (cs >> 4), d8 = (cs & 15) * 8;
      gload_lds16(Kbase + (size_t)(k0 + key) * QKVST + d8, &Ks[buf][idx * 8]);
    }
    #pragma unroll
    for (int pp = 0; pp < 4; pp++){
      int idx = pp * 256 + tid;
      int r = idx >> 5, c = idx & 31;
      int cs = c ^ r;
      int vd = r * 4 + (cs >> 3), k8 = (cs & 7) * 8;
      gload_lds16(Vbase + (size_t)vd * S_LEN + k0 + k8, &Vs[buf][idx * 8]);
    }
  };

  const float sb2 = sinkb[head] * LOG2E;
  bf16x8 qB[8];
  float m, Ll;
  f32x16 O[4];

  auto load_q = [&](int q0){
    const int qw = q0 + w * 32;
    const u16* qrow = QKV + (size_t)(qw + l31) * QKVST + head * HD;
    #pragma unroll
    for (int t = 0; t < 8; t++) qB[t] = *(const bf16x8*)(qrow + t * 16 + hi * 8);
    #pragma unroll
    for (int n = 0; n < 4; n++) O[n] = f32x16{};
  };

  auto do_tile = [&](int cur, int k0, int qw){
    const u16* Kc = Ks[cur];
    const u16* Vc = Vs[cur];
    f32x16 sc0 = {}, sc1 = {};
    const int krow0 = (l31 >> 1);
    const int kc0   = ((l31 & 1) << 4) | hi;
    __builtin_amdgcn_s_setprio(1);
    #pragma unroll
    for (int t = 0; t < 8; t++){
      bf16x8 ka0 = *(const bf16x8*)&Kc[krow0 * 256 + ((kc0 + 2 * t) ^ krow0) * 8];
      bf16x8 ka1 = *(const bf16x8*)&Kc[(16 + krow0) * 256 + ((kc0 + 2 * t) ^ (16 + krow0)) * 8];
      sc0 = __builtin_amdgcn_mfma_f32_32x32x16_bf16(ka0, qB[t], sc0, 0, 0, 0);
      sc1 = __builtin_amdgcn_mfma_f32_32x32x16_bf16(ka1, qB[t], sc1, 0, 0, 0);
    }
    __builtin_amdgcn_s_setprio(0);

    if (k0 + 63 > qw){
      const int qg = qw + l31;
      #pragma unroll
      for (int r = 0; r < 16; r++){
        int keyr = k0 + (r & 3) + 8 * (r >> 2) + 4 * hi;
        if (keyr      > qg) sc0[r] = -1e30f;
        if (keyr + 32 > qg) sc1[r] = -1e30f;
      }
    }
    float mx = sc0[0];
    #pragma unroll
    for (int r = 1; r < 16; r++) mx = fmaxf(mx, sc0[r]);
    #pragma unroll
    for (int r = 0; r < 16; r++) mx = fmaxf(mx, sc1[r]);
    mx = fmaxf(mx, __shfl_xor(mx, 32));
    if (!__all(mx <= m + RESCALE_THR2)){
      float mn = fmaxf(m, mx);
      float sf = exp2f(m - mn);
      m = mn;
      #pragma unroll
      for (int n = 0; n < 4; n++)
        #pragma unroll
        for (int r = 0; r < 16; r++) O[n][r] *= sf;
      Ll *= sf;
    }
    float p0[16], p1[16];
    #pragma unroll
    for (int r = 0; r < 16; r++){ p0[r] = exp2f(sc0[r] - m); Ll += p0[r]; }
    #pragma unroll
    for (int r = 0; r < 16; r++){ p1[r] = exp2f(sc1[r] - m); Ll += p1[r]; }

    __builtin_amdgcn_s_setprio(1);
    #pragma unroll
    for (int c = 0; c < 4; c++){
      const float* ps = (c & 2) ? p1 : p0;
      const int bb = (c & 1) * 8;
      u32 wa = cvtpk(ps[bb + 0], ps[bb + 1]);
      u32 wb = cvtpk(ps[bb + 2], ps[bb + 3]);
      u32 wc = cvtpk(ps[bb + 4], ps[bb + 5]);
      u32 wd = cvtpk(ps[bb + 6], ps[bb + 7]);
      asm("v_permlane32_swap_b32 %0, %1" : "+v"(wa), "+v"(wc));
      asm("v_permlane32_swap_b32 %0, %1" : "+v"(wb), "+v"(wd));
      u32x4 wv_; wv_[0] = wa; wv_[1] = wb; wv_[2] = wc; wv_[3] = wd;
      bf16x8 pf = __builtin_bit_cast(bf16x8, wv_);
      #pragma unroll
      for (int n = 0; n < 4; n++){
        const int vrow = n * 8 + (l31 >> 2);
        const int vcc  = ((l31 & 3) << 3) | (c << 1) | hi;
        bf16x8 va = *(const bf16x8*)&Vc[vrow * 256 + (vcc ^ vrow) * 8];
        O[n] = __builtin_amdgcn_mfma_f32_32x32x16_bf16(va, pf, O[n], 0, 0, 0);
      }
    }
    __builtin_amdgcn_s_setprio(0);
  };

  // epilogue: transpose O via a 32KB arena given as two 16KB halves
  auto epilogue = [&](int q0, bool final_, int rr_, u16* arlo, u16* arhi){
    float l = Ll + __shfl_xor(Ll, 32);
    float inv, lse;
    if (l > 0.f){ inv = 1.f / l; lse = m + __log2f(l); }
    else        { inv = 0.f;     lse = -1e30f; }
    u16* ap = (w < 2) ? arlo + (w * 32 + l31) * 128
                      : arhi + ((w - 2) * 32 + l31) * 128;
    #pragma unroll
    for (int n = 0; n < 4; n++)
      #pragma unroll
      for (int r = 0; r < 16; r++){
        int vd = n * 32 + (r & 3) + 8 * (r >> 2) + 4 * hi;
        int ch = (vd >> 3) ^ (l31 & 15);
        ap[ch * 8 + (vd & 7)] = f2bf(O[n][r] * inv);
      }
    __syncthreads();
    #pragma unroll
    for (int pp = 0; pp < 8; pp++){
      int idx = pp * 256 + tid;
      int row = idx >> 4, c = idx & 15;
      const u16* rp = (row < 64) ? arlo + row * 128 : arhi + (row - 64) * 128;
      u16x8 v = *(const u16x8*)&rp[(c ^ (row & 15)) * 8];
      if (final_){
        *(u16x8*)&AO[(size_t)(q0 + row) * AOST + head * HD + c * 8] = v;
      } else {
        u16* base = PART + (size_t)((head * 8 + p) * 2 + rr_) * PARTSZ;
        *(u16x8*)&base[row * 128 + c * 8] = v;
      }
    }
    if (!final_ && hi == 0){
      u16* base = PART + (size_t)((head * 8 + p) * 2 + rr_) * PARTSZ;
      ((float*)(base + 16384))[w * 32 + l31] = lse;
    }
    __syncthreads();                       // arena reads done before next stage
  };

  const int q0L = qtL * 128;
  if (role == 0){
    // role A: long stripe, tiles [0, 17), sink in init
    load_q(q0L);
    m = sb2; Ll = (hi == 0) ? 1.f : 0.f;
    const int qw = q0L + w * 32;
    stage(0, 0);
    __syncthreads();
    int cur = 0;
    for (int kt = 0; kt < 17; kt++){
      if (kt + 1 < 17) stage(cur ^ 1, kt + 1);
      if (kt * 64 < qw + 32) do_tile(cur, kt * 64, qw);
      __syncthreads();
      cur ^= 1;
    }
    epilogue(q0L, false, 0, &Ks[0][0], &Ks[1][0]);
  } else {
    // role B phase 1: long stripe, tiles [17, 32-2p), no sink;
    // SEAM: last iteration prefetches phase-2 tile 0 into the spare buffer.
    load_q(q0L);
    m = -3.0e38f; Ll = 0.f;
    const int qw = q0L + w * 32;
    const int kt1 = 32 - 2 * p;            // >= 18, so loop runs >= 1 iter
    stage(0, 17);
    __syncthreads();
    int cur = 0;
    for (int kt = 17; kt < kt1; kt++){
      if (kt + 1 < kt1) stage(cur ^ 1, kt + 1);
      else              stage(cur ^ 1, 0);            // phase-2 tile 0
      if (kt * 64 < qw + 32) do_tile(cur, kt * 64, qw);
      __syncthreads();
      cur ^= 1;
    }
    // cur now holds phase-2 tile 0; arena = the DEAD pair (cur^1)
    epilogue(q0L, false, 1, &Ks[cur ^ 1][0], &Vs[cur ^ 1][0]);
    // role B phase 2: short stripe p, tiles [0, 2p+2), sink in init
    const int q0S = p * 128;
    const int qwS = q0S + w * 32;
    load_q(q0S);
    m = sb2; Ll = (hi == 0) ? 1.f : 0.f;
    const int kt2 = 2 * p + 2;
    for (int kt = 0; kt < kt2; kt++){
      if (kt + 1 < kt2) stage(cur ^ 1, kt + 1);
      if (kt * 64 < qwS + 32) do_tile(cur, kt * 64, qwS);
      __syncthreads();
      cur ^= 1;
    }
    epilogue(q0S, true, 0, &Ks[0][0], &Ks[1][0]);
  }
}

// ---------------- merge partials: AO[long stripe] = lse-weighted combine ---
__global__ void merge_kernel(const u16* __restrict__ PART, u16* __restrict__ AO){
  const int sidx = blockIdx.x;             // head*8 + p
  const int h = sidx >> 3, p = sidx & 7;
  const int q0 = (15 - p) * 128;
  const u16* A = PART + (size_t)(sidx * 2 + 0) * PARTSZ;
  const u16* B = PART + (size_t)(sidx * 2 + 1) * PARTSZ;
  const float* lseA = (const float*)(A + 16384);
  const float* lseB = (const float*)(B + 16384);
  #pragma unroll
  for (int it = 0; it < 8; it++){
    int idx = it * 256 + threadIdx.x;      // 2048 chunks: row(128) x c(16)
    int row = idx >> 4, c = (idx & 15) * 8;
    float la = lseA[row], lb = lseB[row];
    float mx = fmaxf(la, lb);
    float wa = exp2f(la - mx), wb = exp2f(lb - mx);
    float inv = 1.f / (wa + wb);
    u16x8 va = *(const u16x8*)&A[row * 128 + c];
    u16x8 vb = *(const u16x8*)&B[row * 128 + c];
    u16x8 o;
    #pragma unroll
    for (int j = 0; j < 8; j++)
      o[j] = f2bf((bf2f(va[j]) * wa + bf2f(vb[j]) * wb) * inv);
    *(u16x8*)&AO[(size_t)(q0 + row) * AOST + h * HD + c] = o;
  }
}

// ---------------- host-side launch ----------------
extern "C" void kernel_launch(void* const* d_in, const int* in_sizes, int n_in,
                              void* d_out, int out_size, void* d_ws, size_t ws_size,
                              hipStream_t stream){
  (void)in_sizes; (void)n_in; (void)out_size; (void)ws_size;
  const float* hs    = (const float*)d_in[0];
  const float* cosv  = (const float*)d_in[1];
  const float* sinv  = (const float*)d_in[2];
  /* d_in[3] attention_mask: pure causal triu(NEG,1) - implemented directly */
  const float* Wq    = (const float*)d_in[4];
  const float* Wk    = (const float*)d_in[5];
  const float* Wv    = (const float*)d_in[6];
  const float* Wo    = (const float*)d_in[7];
  const float* sinkb = (const float*)d_in[8];
  float* out = (float*)d_out;

  char* ws = (char*)d_ws;
  u16* XB    = (u16*)(ws);                  //  8,388,608  X bf16 [2048][2048]
  u16* WQKVB = (u16*)(ws + 8388608);        // 25,165,824  Wqkv bf16 [6144][2048]
  u16* WOB   = (u16*)(ws + 33554432);       // 16,777,216  Wo bf16 [2048][4096]
  u16* QKV   = (u16*)(ws + 50331648);       // 25,165,824  QKV bf16 [2048][6144]
  u16* VT    = (u16*)(ws + 75497472);       //  4,194,304  V^T bf16 [8][128][2048]
  u16* AO    = (u16*)(ws + 79691776);       // 16,777,216  attn out bf16 [2048][4096]
  u16* PART  = (u16*)(ws);                  // 17,039,360  partials (XB region,
                                            //   dead after the QKV GEMM)

  cvt_all_kernel<<<24576, 256, 0, stream>>>((const f32x4*)hs, (const f32x4*)Wq,
                                            (const f32x4*)Wk, (const f32x4*)Wv,
                                            (const f32x4*)Wo, (u16x4*)ws);

  // fused QKV projection + RoPE + Q-scale(log2e): m97 geometry (128/128/32)
  gemm_bt_kernel<1, 1, 128, 128, 32><<<dim3(48, 16), 256, 0, stream>>>(XB, WQKVB, QKV, 2048, 6144, 2048, cosv, sinv);

  vtrans_kernel<<<8192, 256, 0, stream>>>(QKV, VT);

  // attention: 512 uniform-17-tile blocks (role A: b<256, role B: b>=256)
  attn_kernel<<<dim3(512), 256, 0, stream>>>(QKV, VT, sinkb, AO, PART);

  // merge split (long) stripes: 256 stripes, lse-weighted combine
  merge_kernel<<<dim3(256), 256, 0, stream>>>(PART, AO);

  // output projection (f32 out): 128/64/64 -> 16 MFMA/barrier (R16 config;
  // R17's BK=32 halved MFMA/barrier and doubled barriers -> 58->78us)
  gemm_bt_kernel<0, 0, 128, 64, 64><<<dim3(32, 16), 256, 0, stream>>>(AO, WOB, out, 2048, 2048, 4096, nullptr, nullptr);
}

// Round 19
// 223.400 us; speedup vs baseline: 1.0566x; 1.0061x over previous
//
#include <hip/hip_runtime.h>

typedef unsigned short u16;
typedef unsigned int   u32;
typedef __bf16  bf16x8 __attribute__((ext_vector_type(8)));
typedef float   f32x4  __attribute__((ext_vector_type(4)));
typedef float   f32x16 __attribute__((ext_vector_type(16)));
typedef u16     u16x4  __attribute__((ext_vector_type(4)));
typedef u16     u16x8  __attribute__((ext_vector_type(8)));
typedef u32     u32x4  __attribute__((ext_vector_type(4)));

#define S_LEN 2048
#define NH 32
#define NKVH 8
#define HD 128
#define QKVST 6144          /* packed QKV row stride  */
#define AOST  4096          /* attn-out row stride    */
#define ATT_SCALE 0.08838834764831845f
#define LOG2E 1.4426950408889634f
#define QSC2 (ATT_SCALE * LOG2E)
#define RESCALE_THR2 11.5f
#define PARTSZ 16640        /* u16 per partial: 128x128 bf16 O + 128 f32 lse */

__device__ __forceinline__ u16 f2bf(float f){
  u32 u = __builtin_bit_cast(u32, f);
  u += 0x7FFFu + ((u >> 16) & 1u);
  return (u16)(u >> 16);
}
__device__ __forceinline__ float bf2f(u16 h){
  u32 u = ((u32)h) << 16;
  return __builtin_bit_cast(float, u);
}
__device__ __forceinline__ u32 cvtpk(float lo, float hi){
  u32 d;
  asm("v_cvt_pk_bf16_f32 %0, %1, %2" : "=v"(d) : "v"(lo), "v"(hi));
  return d;
}
// async global->LDS, 16B per lane. Dest must be wave-uniform base + lane*16.
__device__ __forceinline__ void gload_lds16(const u16* g, u16* l){
  __builtin_amdgcn_global_load_lds(
      (const __attribute__((address_space(1))) void*)g,
      (__attribute__((address_space(3))) void*)l, 16, 0, 0);
}

// ------------- fused f32 -> bf16 convert of ALL inputs (one launch) --------
__global__ void cvt_all_kernel(const f32x4* __restrict__ hs, const f32x4* __restrict__ wq,
                               const f32x4* __restrict__ wk, const f32x4* __restrict__ wv,
                               const f32x4* __restrict__ wo, u16x4* __restrict__ out){
  int i = blockIdx.x * 256 + threadIdx.x;          // 0 .. 6291455
  const f32x4* src; int off;
  if      (i < 1048576){ src = hs; off = i; }
  else if (i < 3145728){ src = wq; off = i - 1048576; }
  else if (i < 3670016){ src = wk; off = i - 3145728; }
  else if (i < 4194304){ src = wv; off = i - 3670016; }
  else                 { src = wo; off = i - 4194304; }
  f32x4 v = src[off];
  u16x4 o;
  o[0] = f2bf(v[0]); o[1] = f2bf(v[1]); o[2] = f2bf(v[2]); o[3] = f2bf(v[3]);
  out[i] = o;
}

// ---------------- GEMM: C[M][N] = X[M][K] @ W[N][K]^T (bf16 in, f32 acc) ----
// QKV: 128/128/32 (m97 geometry, 32KB LDS, 16 MFMA/barrier). O-proj:
// 128/64/64 (48KB LDS, 16 MFMA/barrier). [R17: BK=32 at NJ=2 -> 8
// MFMA/barrier + 2x barriers = drain-dominated. Keep >=16 MFMA/barrier.]
template<int OUT_BF16, int ROPE, int BM, int BN, int BK>
__global__ __launch_bounds__(256, 2)
void gemm_bt_kernel(const u16* __restrict__ X, const u16* __restrict__ W,
                    void* __restrict__ Cv, int M, int N, int K,
                    const float* __restrict__ cosv, const float* __restrict__ sinv){
  const int NS = BK / 32;
  __shared__ __align__(16) u16 As[2][NS][BM * 32];
  __shared__ __align__(16) u16 Bs[2][NS][BN * 32];
  const int MI = BM / 32, NJ = BN / 32;
  const int m0 = blockIdx.y * BM, n0 = blockIdx.x * BN;
  const int tid = threadIdx.x;
  const int wave = tid >> 6, lane = tid & 63;
  const int wm = wave >> 1, wn = wave & 1;
  const int g = lane >> 4, ln = lane & 15;
  const int r0 = tid >> 2;
  const int cc = (tid & 3) * 8;
  f32x4 acc[MI][NJ] = {};
  const u16* xa0 = X + (size_t)(m0 + r0) * K + cc;
  const u16* xa1 = X + (size_t)(m0 + r0 + 64) * K + cc;
  const u16* wb0 = W + (size_t)(n0 + r0) * K + cc;
  const u16* wb1 = W + (size_t)(n0 + r0 + 64) * K + cc;

  auto stage = [&](int buf, int k0){
    #pragma unroll
    for (int s = 0; s < NS; s++){
      const int kc = k0 + s * 32;
      gload_lds16(xa0 + kc, &As[buf][s][tid * 8]);
      if (BM == 128) gload_lds16(xa1 + kc, &As[buf][s][2048 + tid * 8]);
      gload_lds16(wb0 + kc, &Bs[buf][s][tid * 8]);
      if (BN == 128) gload_lds16(wb1 + kc, &Bs[buf][s][2048 + tid * 8]);
    }
  };

  stage(0, 0);
  __syncthreads();
  int cur = 0;
  for (int k0 = 0; k0 < K; k0 += BK){
    if (k0 + BK < K) stage(cur ^ 1, k0 + BK);
    #pragma unroll
    for (int s = 0; s < NS; s++){
      bf16x8 a[MI], b[NJ];
      #pragma unroll
      for (int f = 0; f < MI; f++) a[f] = *(const bf16x8*)&As[cur][s][(wm * (BM / 2) + f * 16 + ln) * 32 + g * 8];
      #pragma unroll
      for (int f = 0; f < NJ; f++) b[f] = *(const bf16x8*)&Bs[cur][s][(wn * (BN / 2) + f * 16 + ln) * 32 + g * 8];
      __builtin_amdgcn_s_setprio(1);
      #pragma unroll
      for (int i = 0; i < MI; i++)
        #pragma unroll
        for (int j = 0; j < NJ; j++)
          acc[i][j] = __builtin_amdgcn_mfma_f32_16x16x32_bf16(a[i], b[j], acc[i][j], 0, 0, 0);
      __builtin_amdgcn_s_setprio(0);
    }
    __syncthreads();
    cur ^= 1;
  }
  if (ROPE && BN == 128){
    if (wn == 0 && n0 < 5120){
      #pragma unroll
      for (int i = 0; i < MI; i++)
        #pragma unroll
        for (int r = 0; r < 4; r++){
          const int row = m0 + wm * (BM / 2) + i * 16 + g * 4 + r;
          #pragma unroll
          for (int j = 0; j < 2; j++){
            const int d = j * 16 + ln;
            float c  = cosv[row * 64 + d];
            float sn = sinv[row * 64 + d];
            float x0 = acc[i][j][r], x1 = acc[i][j + 2][r];
            acc[i][j][r]     = x0 * c - x1 * sn;
            acc[i][j + 2][r] = x1 * c + x0 * sn;
          }
        }
    }
    if (n0 < 4096){
      #pragma unroll
      for (int i = 0; i < MI; i++)
        #pragma unroll
        for (int j = 0; j < NJ; j++)
          #pragma unroll
          for (int r = 0; r < 4; r++) acc[i][j][r] *= QSC2;
    }
  }
  #pragma unroll
  for (int i = 0; i < MI; i++)
    #pragma unroll
    for (int j = 0; j < NJ; j++)
      #pragma unroll
      for (int r = 0; r < 4; r++){
        int row = m0 + wm * (BM / 2) + i * 16 + g * 4 + r;
        int col = n0 + wn * (BN / 2) + j * 16 + ln;
        if (OUT_BF16) ((u16*)Cv)[(size_t)row * N + col] = f2bf(acc[i][j][r]);
        else          ((float*)Cv)[(size_t)row * N + col] = acc[i][j][r];
      }
}

// ---------------- V transpose: VT[kvh][vd][s] from packed QKV -------------
__global__ void vtrans_kernel(const u16* __restrict__ QKV, u16* __restrict__ VT){
  int idx = blockIdx.x * 256 + threadIdx.x;
  if (idx >= NKVH * HD * S_LEN) return;
  int s   = idx & (S_LEN - 1);
  int vd  = (idx >> 11) & (HD - 1);
  int kvh = idx >> 18;
  VT[idx] = QKV[(size_t)s * QKVST + 5120 + kvh * HD + vd];
}

// ---------------- causal flash attention, stream-K split (18/16 roles) -----
// R16's verified structure with BALANCED roles: role A = long stripe tiles
// [0,18) + 1 epilogue + 1 cold stage; role B = long stripe [18,32-2p) +
// short stripe p (2p+2 tiles) + 2 epilogues + 2 cold stages. A=18+1epi,
// B=16+2epi: role finish times equalized (R16's 17/17 left B ~2us longer
// and B set the makespan). p=7: B phase-1 is empty (harmless stage of
// valid-but-unused rows; l==0 guard -> lse=-1e30 -> zero merge weight).
__global__ __launch_bounds__(256, 2)
void attn_kernel(const u16* __restrict__ QKV, const u16* __restrict__ VT,
                 const float* __restrict__ sinkb, u16* __restrict__ AO,
                 u16* __restrict__ PART){
  __shared__ __align__(16) u16 Ks[2][32 * 256];   // 64 keys: key-pair rows, 512B
  __shared__ __align__(16) u16 Vs[2][32 * 256];   // 128 vd: vd-quad rows, 512B
  const int b    = blockIdx.x;
  const int kvh  = b & 7;                  // XCD-aligned kv-head
  const int head = kvh * 4 + ((b >> 3) & 3);
  const int p    = (b >> 5) & 7;           // pair index 0..7
  const int role = b >> 8;                 // 0 = A, 1 = B
  const int qtL  = 15 - p;
  const int tid  = threadIdx.x;
  const int w    = tid >> 6;
  const int lane = tid & 63;
  const int l31  = lane & 31, hi = lane >> 5;

  const u16* Kbase = QKV + 4096 + kvh * HD;           // + row*QKVST
  const u16* Vbase = VT + (size_t)kvh * HD * S_LEN;   // + vd*S_LEN + key

  auto stage = [&](int buf, int kt){
    const int k0 = kt * 64;
    #pragma unroll
    for (int pp = 0; pp < 4; pp++){
      int idx = pp * 256 + tid;
      int r = idx >> 5, c = idx & 31;
      int cs = c ^ r;
      int key = r * 2 + (cs >> 4), d8 = (cs & 15) * 8;
      gload_lds16(Kbase + (size_t)(k0 + key) * QKVST + d8, &Ks[buf][idx * 8]);
    }
    #pragma unroll
    for (int pp = 0; pp < 4; pp++){
      int idx = pp * 256 + tid;
      int r = idx >> 5, c = idx & 31;
      int cs = c ^ r;
      int vd = r * 4 + (cs >> 3), k8 = (cs & 7) * 8;
      gload_lds16(Vbase + (size_t)vd * S_LEN + k0 + k8, &Vs[buf][idx * 8]);
    }
  };

  const float sb2 = sinkb[head] * LOG2E;
  bf16x8 qB[8];
  float m, Ll;
  f32x16 O[4];

  auto load_q = [&](int q0){
    const int qw = q0 + w * 32;
    const u16* qrow = QKV + (size_t)(qw + l31) * QKVST + head * HD;
    #pragma unroll
    for (int t = 0; t < 8; t++) qB[t] = *(const bf16x8*)(qrow + t * 16 + hi * 8);
    #pragma unroll
    for (int n = 0; n < 4; n++) O[n] = f32x16{};
  };

  auto do_tile = [&](int cur, int k0, int qw){
    const u16* Kc = Ks[cur];
    const u16* Vc = Vs[cur];
    f32x16 sc0 = {}, sc1 = {};
    const int krow0 = (l31 >> 1);
    const int kc0   = ((l31 & 1) << 4) | hi;
    __builtin_amdgcn_s_setprio(1);
    #pragma unroll
    for (int t = 0; t < 8; t++){
      bf16x8 ka0 = *(const bf16x8*)&Kc[krow0 * 256 + ((kc0 + 2 * t) ^ krow0) * 8];
      bf16x8 ka1 = *(const bf16x8*)&Kc[(16 + krow0) * 256 + ((kc0 + 2 * t) ^ (16 + krow0)) * 8];
      sc0 = __builtin_amdgcn_mfma_f32_32x32x16_bf16(ka0, qB[t], sc0, 0, 0, 0);
      sc1 = __builtin_amdgcn_mfma_f32_32x32x16_bf16(ka1, qB[t], sc1, 0, 0, 0);
    }
    __builtin_amdgcn_s_setprio(0);

    if (k0 + 63 > qw){
      const int qg = qw + l31;
      #pragma unroll
      for (int r = 0; r < 16; r++){
        int keyr = k0 + (r & 3) + 8 * (r >> 2) + 4 * hi;
        if (keyr      > qg) sc0[r] = -1e30f;
        if (keyr + 32 > qg) sc1[r] = -1e30f;
      }
    }
    float mx = sc0[0];
    #pragma unroll
    for (int r = 1; r < 16; r++) mx = fmaxf(mx, sc0[r]);
    #pragma unroll
    for (int r = 0; r < 16; r++) mx = fmaxf(mx, sc1[r]);
    mx = fmaxf(mx, __shfl_xor(mx, 32));
    if (!__all(mx <= m + RESCALE_THR2)){
      float mn = fmaxf(m, mx);
      float sf = exp2f(m - mn);
      m = mn;
      #pragma unroll
      for (int n = 0; n < 4; n++)
        #pragma unroll
        for (int r = 0; r < 16; r++) O[n][r] *= sf;
      Ll *= sf;
    }
    float p0[16], p1[16];
    #pragma unroll
    for (int r = 0; r < 16; r++){ p0[r] = exp2f(sc0[r] - m); Ll += p0[r]; }
    #pragma unroll
    for (int r = 0; r < 16; r++){ p1[r] = exp2f(sc1[r] - m); Ll += p1[r]; }

    __builtin_amdgcn_s_setprio(1);
    #pragma unroll
    for (int c = 0; c < 4; c++){
      const float* ps = (c & 2) ? p1 : p0;
      const int bb = (c & 1) * 8;
      u32 wa = cvtpk(ps[bb + 0], ps[bb + 1]);
      u32 wb = cvtpk(ps[bb + 2], ps[bb + 3]);
      u32 wc = cvtpk(ps[bb + 4], ps[bb + 5]);
      u32 wd = cvtpk(ps[bb + 6], ps[bb + 7]);
      asm("v_permlane32_swap_b32 %0, %1" : "+v"(wa), "+v"(wc));
      asm("v_permlane32_swap_b32 %0, %1" : "+v"(wb), "+v"(wd));
      u32x4 wv_; wv_[0] = wa; wv_[1] = wb; wv_[2] = wc; wv_[3] = wd;
      bf16x8 pf = __builtin_bit_cast(bf16x8, wv_);
      #pragma unroll
      for (int n = 0; n < 4; n++){
        const int vrow = n * 8 + (l31 >> 2);
        const int vcc  = ((l31 & 3) << 3) | (c << 1) | hi;
        bf16x8 va = *(const bf16x8*)&Vc[vrow * 256 + (vcc ^ vrow) * 8];
        O[n] = __builtin_amdgcn_mfma_f32_32x32x16_bf16(va, pf, O[n], 0, 0, 0);
      }
    }
    __builtin_amdgcn_s_setprio(0);
  };

  // run tiles [kt0, kt1) of stripe at q0; buffers start at cur=0
  auto run = [&](int q0, int kt0, int kt1){
    const int qw = q0 + w * 32;
    stage(0, kt0);
    __syncthreads();
    int cur = 0;
    for (int kt = kt0; kt < kt1; kt++){
      if (kt + 1 < kt1) stage(cur ^ 1, kt + 1);
      if (kt * 64 < qw + 32) do_tile(cur, kt * 64, qw);
      __syncthreads();
      cur ^= 1;
    }
  };

  // epilogue: transpose O via dead K buffers; final -> AO, else -> PART+lse
  auto epilogue = [&](int q0, bool final_, int rr_){
    float l = Ll + __shfl_xor(Ll, 32);
    float inv, lse;
    if (l > 0.f){ inv = 1.f / l; lse = m + __log2f(l); }
    else        { inv = 0.f;     lse = -1e30f; }
    u16* arena = &Ks[0][0];                // 32KB (both K buffers, dead)
    #pragma unroll
    for (int n = 0; n < 4; n++)
      #pragma unroll
      for (int r = 0; r < 16; r++){
        int vd = n * 32 + (r & 3) + 8 * (r >> 2) + 4 * hi;
        int ch = (vd >> 3) ^ (l31 & 15);
        arena[w * 4096 + l31 * 128 + ch * 8 + (vd & 7)] = f2bf(O[n][r] * inv);
      }
    __syncthreads();
    if (final_){
      #pragma unroll
      for (int pp = 0; pp < 8; pp++){
        int idx = pp * 256 + tid;
        int row = idx >> 4, c = idx & 15;
        u16x8 v = *(const u16x8*)&arena[row * 128 + ((c ^ (row & 15)) * 8)];
        *(u16x8*)&AO[(size_t)(q0 + row) * AOST + head * HD + c * 8] = v;
      }
    } else {
      u16* base = PART + (size_t)((head * 8 + p) * 2 + rr_) * PARTSZ;
      #pragma unroll
      for (int pp = 0; pp < 8; pp++){
        int idx = pp * 256 + tid;
        int row = idx >> 4, c = idx & 15;
        u16x8 v = *(const u16x8*)&arena[row * 128 + ((c ^ (row & 15)) * 8)];
        *(u16x8*)&base[row * 128 + c * 8] = v;
      }
      if (hi == 0) ((float*)(base + 16384))[w * 32 + l31] = lse;
    }
    __syncthreads();                       // arena reads done before next stage
  };

  const int q0L = qtL * 128;
  if (role == 0){
    // role A: long stripe, tiles [0, 18), sink in init
    load_q(q0L);
    m = sb2; Ll = (hi == 0) ? 1.f : 0.f;
    run(q0L, 0, 18);
    epilogue(q0L, false, 0);
  } else {
    // role B phase 1: long stripe, tiles [18, 32-2p), no sink
    load_q(q0L);
    m = -3.0e38f; Ll = 0.f;
    run(q0L, 18, 32 - 2 * p);
    epilogue(q0L, false, 1);
    // role B phase 2: short stripe p, all 2p+2 tiles, sink in init
    const int q0S = p * 128;
    load_q(q0S);
    m = sb2; Ll = (hi == 0) ? 1.f : 0.f;
    run(q0S, 0, 2 * p + 2);
    epilogue(q0S, true, 0);
  }
}

// ---------------- merge partials: AO[long stripe] = lse-weighted combine ---
__global__ void merge_kernel(const u16* __restrict__ PART, u16* __restrict__ AO){
  const int sidx = blockIdx.x;             // head*8 + p
  const int h = sidx >> 3, p = sidx & 7;
  const int q0 = (15 - p) * 128;
  const u16* A = PART + (size_t)(sidx * 2 + 0) * PARTSZ;
  const u16* B = PART + (size_t)(sidx * 2 + 1) * PARTSZ;
  const float* lseA = (const float*)(A + 16384);
  const float* lseB = (const float*)(B + 16384);
  #pragma unroll
  for (int it = 0; it < 8; it++){
    int idx = it * 256 + threadIdx.x;      // 2048 chunks: row(128) x c(16)
    int row = idx >> 4, c = (idx & 15) * 8;
    float la = lseA[row], lb = lseB[row];
    float mx = fmaxf(la, lb);
    float wa = exp2f(la - mx), wb = exp2f(lb - mx);
    float inv = 1.f / (wa + wb);
    u16x8 va = *(const u16x8*)&A[row * 128 + c];
    u16x8 vb = *(const u16x8*)&B[row * 128 + c];
    u16x8 o;
    #pragma unroll
    for (int j = 0; j < 8; j++)
      o[j] = f2bf((bf2f(va[j]) * wa + bf2f(vb[j]) * wb) * inv);
    *(u16x8*)&AO[(size_t)(q0 + row) * AOST + h * HD + c] = o;
  }
}

// ---------------- host-side launch ----------------
extern "C" void kernel_launch(void* const* d_in, const int* in_sizes, int n_in,
                              void* d_out, int out_size, void* d_ws, size_t ws_size,
                              hipStream_t stream){
  (void)in_sizes; (void)n_in; (void)out_size; (void)ws_size;
  const float* hs    = (const float*)d_in[0];
  const float* cosv  = (const float*)d_in[1];
  const float* sinv  = (const float*)d_in[2];
  /* d_in[3] attention_mask: pure causal triu(NEG,1) - implemented directly */
  const float* Wq    = (const float*)d_in[4];
  const float* Wk    = (const float*)d_in[5];
  const float* Wv    = (const float*)d_in[6];
  const float* Wo    = (const float*)d_in[7];
  const float* sinkb = (const float*)d_in[8];
  float* out = (float*)d_out;

  char* ws = (char*)d_ws;
  u16* XB    = (u16*)(ws);                  //  8,388,608  X bf16 [2048][2048]
  u16* WQKVB = (u16*)(ws + 8388608);        // 25,165,824  Wqkv bf16 [6144][2048]
  u16* WOB   = (u16*)(ws + 33554432);       // 16,777,216  Wo bf16 [2048][4096]
  u16* QKV   = (u16*)(ws + 50331648);       // 25,165,824  QKV bf16 [2048][6144]
  u16* VT    = (u16*)(ws + 75497472);       //  4,194,304  V^T bf16 [8][128][2048]
  u16* AO    = (u16*)(ws + 79691776);       // 16,777,216  attn out bf16 [2048][4096]
  u16* PART  = (u16*)(ws);                  // 17,039,360  partials (XB region,
                                            //   dead after the QKV GEMM)

  cvt_all_kernel<<<24576, 256, 0, stream>>>((const f32x4*)hs, (const f32x4*)Wq,
                                            (const f32x4*)Wk, (const f32x4*)Wv,
                                            (const f32x4*)Wo, (u16x4*)ws);

  // fused QKV projection + RoPE + Q-scale(log2e): m97 geometry (128/128/32)
  gemm_bt_kernel<1, 1, 128, 128, 32><<<dim3(48, 16), 256, 0, stream>>>(XB, WQKVB, QKV, 2048, 6144, 2048, cosv, sinv);

  vtrans_kernel<<<8192, 256, 0, stream>>>(QKV, VT);

  // attention: 512 blocks, balanced 18/16-tile roles (A: b<256, B: b>=256)
  attn_kernel<<<dim3(512), 256, 0, stream>>>(QKV, VT, sinkb, AO, PART);

  // merge split (long) stripes: 256 stripes, lse-weighted combine
  merge_kernel<<<dim3(256), 256, 0, stream>>>(PART, AO);

  // output projection (f32 out): 128/64/64, 16 MFMA/barrier
  gemm_bt_kernel<0, 0, 128, 64, 64><<<dim3(32, 16), 256, 0, stream>>>(AO, WOB, out, 2048, 2048, 4096, nullptr, nullptr);
}

// Round 20
// 219.959 us; speedup vs baseline: 1.0731x; 1.0156x over previous
//
#include <hip/hip_runtime.h>

typedef unsigned short u16;
typedef unsigned int   u32;
typedef __bf16  bf16x8 __attribute__((ext_vector_type(8)));
typedef float   f32x4  __attribute__((ext_vector_type(4)));
typedef float   f32x16 __attribute__((ext_vector_type(16)));
typedef u16     u16x4  __attribute__((ext_vector_type(4)));
typedef u16     u16x8  __attribute__((ext_vector_type(8)));
typedef u32     u32x4  __attribute__((ext_vector_type(4)));

#define S_LEN 2048
#define NH 32
#define NKVH 8
#define HD 128
#define QKVST 6144          /* packed QKV row stride  */
#define AOST  4096          /* attn-out row stride    */
#define ATT_SCALE 0.08838834764831845f
#define LOG2E 1.4426950408889634f
#define QSC2 (ATT_SCALE * LOG2E)
#define RESCALE_THR2 11.5f
#define PARTSZ 16640        /* u16 per partial: 128x128 bf16 O + 128 f32 lse */

__device__ __forceinline__ u16 f2bf(float f){
  u32 u = __builtin_bit_cast(u32, f);
  u += 0x7FFFu + ((u >> 16) & 1u);
  return (u16)(u >> 16);
}
__device__ __forceinline__ float bf2f(u16 h){
  u32 u = ((u32)h) << 16;
  return __builtin_bit_cast(float, u);
}
__device__ __forceinline__ u32 cvtpk(float lo, float hi){
  u32 d;
  asm("v_cvt_pk_bf16_f32 %0, %1, %2" : "=v"(d) : "v"(lo), "v"(hi));
  return d;
}
// async global->LDS, 16B per lane. Dest must be wave-uniform base + lane*16.
__device__ __forceinline__ void gload_lds16(const u16* g, u16* l){
  __builtin_amdgcn_global_load_lds(
      (const __attribute__((address_space(1))) void*)g,
      (__attribute__((address_space(3))) void*)l, 16, 0, 0);
}

// ------------- fused f32 -> bf16 convert of ALL inputs (one launch) --------
__global__ void cvt_all_kernel(const f32x4* __restrict__ hs, const f32x4* __restrict__ wq,
                               const f32x4* __restrict__ wk, const f32x4* __restrict__ wv,
                               const f32x4* __restrict__ wo, u16x4* __restrict__ out){
  int i = blockIdx.x * 256 + threadIdx.x;          // 0 .. 6291455
  const f32x4* src; int off;
  if      (i < 1048576){ src = hs; off = i; }
  else if (i < 3145728){ src = wq; off = i - 1048576; }
  else if (i < 3670016){ src = wk; off = i - 3145728; }
  else if (i < 4194304){ src = wv; off = i - 3670016; }
  else                 { src = wo; off = i - 4194304; }
  f32x4 v = src[off];
  u16x4 o;
  o[0] = f2bf(v[0]); o[1] = f2bf(v[1]); o[2] = f2bf(v[2]); o[3] = f2bf(v[3]);
  out[i] = o;
}

// ---------------- GEMM: C[M][N] = X[M][K] @ W[N][K]^T (bf16 in, f32 acc) ----
// QKV: 128/128/32 (m97 geometry). O-proj: 128/64/64. Both >=16 MFMA/barrier.
// NEW (R20): both-sides LDS XOR swizzle, chunk' = chunk ^ ((row>>1)&3).
// Stage: pre-swizzled GLOBAL source column, linear LDS dest (gload_lds rule).
// Read: same XOR. Banks: (row&1)*16 + (chunk')*4 -> rows 0..7 hit 8 distinct
// groups -> 2-way (free) instead of the prior 8-way on every ds_read_b128.
template<int OUT_BF16, int ROPE, int BM, int BN, int BK>
__global__ __launch_bounds__(256, 2)
void gemm_bt_kernel(const u16* __restrict__ X, const u16* __restrict__ W,
                    void* __restrict__ Cv, int M, int N, int K,
                    const float* __restrict__ cosv, const float* __restrict__ sinv){
  const int NS = BK / 32;
  __shared__ __align__(16) u16 As[2][NS][BM * 32];
  __shared__ __align__(16) u16 Bs[2][NS][BN * 32];
  const int MI = BM / 32, NJ = BN / 32;
  const int m0 = blockIdx.y * BM, n0 = blockIdx.x * BN;
  const int tid = threadIdx.x;
  const int wave = tid >> 6, lane = tid & 63;
  const int wm = wave >> 1, wn = wave & 1;
  const int g = lane >> 4, ln = lane & 15;
  const int r0 = tid >> 2;            // rows 0..63 (tid*16B == linear LDS dest)
  // source chunk pre-swizzled: chunk' = (tid&3) ^ ((row>>1)&3)
  const int cc = (((tid & 3) ^ ((r0 >> 1) & 3)) * 8);
  f32x4 acc[MI][NJ] = {};
  const u16* xa0 = X + (size_t)(m0 + r0) * K + cc;
  const u16* xa1 = X + (size_t)(m0 + r0 + 64) * K + (((tid & 3) ^ (((r0 + 64) >> 1) & 3)) * 8);
  const u16* wb0 = W + (size_t)(n0 + r0) * K + cc;
  const u16* wb1 = W + (size_t)(n0 + r0 + 64) * K + (((tid & 3) ^ (((r0 + 64) >> 1) & 3)) * 8);

  auto stage = [&](int buf, int k0){
    #pragma unroll
    for (int s = 0; s < NS; s++){
      const int kc = k0 + s * 32;
      gload_lds16(xa0 + kc, &As[buf][s][tid * 8]);
      if (BM == 128) gload_lds16(xa1 + kc, &As[buf][s][2048 + tid * 8]);
      gload_lds16(wb0 + kc, &Bs[buf][s][tid * 8]);
      if (BN == 128) gload_lds16(wb1 + kc, &Bs[buf][s][2048 + tid * 8]);
    }
  };

  stage(0, 0);
  __syncthreads();
  int cur = 0;
  for (int k0 = 0; k0 < K; k0 += BK){
    if (k0 + BK < K) stage(cur ^ 1, k0 + BK);
    #pragma unroll
    for (int s = 0; s < NS; s++){
      bf16x8 a[MI], b[NJ];
      #pragma unroll
      for (int f = 0; f < MI; f++){
        const int row = wm * (BM / 2) + f * 16 + ln;
        a[f] = *(const bf16x8*)&As[cur][s][row * 32 + ((g ^ ((row >> 1) & 3)) * 8)];
      }
      #pragma unroll
      for (int f = 0; f < NJ; f++){
        const int row = wn * (BN / 2) + f * 16 + ln;
        b[f] = *(const bf16x8*)&Bs[cur][s][row * 32 + ((g ^ ((row >> 1) & 3)) * 8)];
      }
      __builtin_amdgcn_s_setprio(1);
      #pragma unroll
      for (int i = 0; i < MI; i++)
        #pragma unroll
        for (int j = 0; j < NJ; j++)
          acc[i][j] = __builtin_amdgcn_mfma_f32_16x16x32_bf16(a[i], b[j], acc[i][j], 0, 0, 0);
      __builtin_amdgcn_s_setprio(0);
    }
    __syncthreads();
    cur ^= 1;
  }
  if (ROPE && BN == 128){
    if (wn == 0 && n0 < 5120){
      #pragma unroll
      for (int i = 0; i < MI; i++)
        #pragma unroll
        for (int r = 0; r < 4; r++){
          const int row = m0 + wm * (BM / 2) + i * 16 + g * 4 + r;
          #pragma unroll
          for (int j = 0; j < 2; j++){
            const int d = j * 16 + ln;
            float c  = cosv[row * 64 + d];
            float sn = sinv[row * 64 + d];
            float x0 = acc[i][j][r], x1 = acc[i][j + 2][r];
            acc[i][j][r]     = x0 * c - x1 * sn;
            acc[i][j + 2][r] = x1 * c + x0 * sn;
          }
        }
    }
    if (n0 < 4096){
      #pragma unroll
      for (int i = 0; i < MI; i++)
        #pragma unroll
        for (int j = 0; j < NJ; j++)
          #pragma unroll
          for (int r = 0; r < 4; r++) acc[i][j][r] *= QSC2;
    }
  }
  #pragma unroll
  for (int i = 0; i < MI; i++)
    #pragma unroll
    for (int j = 0; j < NJ; j++)
      #pragma unroll
      for (int r = 0; r < 4; r++){
        int row = m0 + wm * (BM / 2) + i * 16 + g * 4 + r;
        int col = n0 + wn * (BN / 2) + j * 16 + ln;
        if (OUT_BF16) ((u16*)Cv)[(size_t)row * N + col] = f2bf(acc[i][j][r]);
        else          ((float*)Cv)[(size_t)row * N + col] = acc[i][j][r];
      }
}

// ---------------- V transpose: VT[kvh][vd][s] from packed QKV -------------
__global__ void vtrans_kernel(const u16* __restrict__ QKV, u16* __restrict__ VT){
  int idx = blockIdx.x * 256 + threadIdx.x;
  if (idx >= NKVH * HD * S_LEN) return;
  int s   = idx & (S_LEN - 1);
  int vd  = (idx >> 11) & (HD - 1);
  int kvh = idx >> 18;
  VT[idx] = QKV[(size_t)s * QKVST + 5120 + kvh * HD + vd];
}

// ---------------- causal flash attention, stream-K split (18/16 roles) -----
// (unchanged from R19 — verified best: 512 blocks, balanced A=18+1epi /
//  B=16+2epi roles, lse-merge, swapped-operand 32x32 MFMA, in-lane softmax)
__global__ __launch_bounds__(256, 2)
void attn_kernel(const u16* __restrict__ QKV, const u16* __restrict__ VT,
                 const float* __restrict__ sinkb, u16* __restrict__ AO,
                 u16* __restrict__ PART){
  __shared__ __align__(16) u16 Ks[2][32 * 256];   // 64 keys: key-pair rows, 512B
  __shared__ __align__(16) u16 Vs[2][32 * 256];   // 128 vd: vd-quad rows, 512B
  const int b    = blockIdx.x;
  const int kvh  = b & 7;                  // XCD-aligned kv-head
  const int head = kvh * 4 + ((b >> 3) & 3);
  const int p    = (b >> 5) & 7;           // pair index 0..7
  const int role = b >> 8;                 // 0 = A, 1 = B
  const int qtL  = 15 - p;
  const int tid  = threadIdx.x;
  const int w    = tid >> 6;
  const int lane = tid & 63;
  const int l31  = lane & 31, hi = lane >> 5;

  const u16* Kbase = QKV + 4096 + kvh * HD;           // + row*QKVST
  const u16* Vbase = VT + (size_t)kvh * HD * S_LEN;   // + vd*S_LEN + key

  auto stage = [&](int buf, int kt){
    const int k0 = kt * 64;
    #pragma unroll
    for (int pp = 0; pp < 4; pp++){
      int idx = pp * 256 + tid;
      int r = idx >> 5, c = idx & 31;
      int cs = c ^ r;
      int key = r * 2 + (cs >> 4), d8 = (cs & 15) * 8;
      gload_lds16(Kbase + (size_t)(k0 + key) * QKVST + d8, &Ks[buf][idx * 8]);
    }
    #pragma unroll
    for (int pp = 0; pp < 4; pp++){
      int idx = pp * 256 + tid;
      int r = idx >> 5, c = idx & 31;
      int cs = c ^ r;
      int vd = r * 4 + (cs >> 3), k8 = (cs & 7) * 8;
      gload_lds16(Vbase + (size_t)vd * S_LEN + k0 + k8, &Vs[buf][idx * 8]);
    }
  };

  const float sb2 = sinkb[head] * LOG2E;
  bf16x8 qB[8];
  float m, Ll;
  f32x16 O[4];

  auto load_q = [&](int q0){
    const int qw = q0 + w * 32;
    const u16* qrow = QKV + (size_t)(qw + l31) * QKVST + head * HD;
    #pragma unroll
    for (int t = 0; t < 8; t++) qB[t] = *(const bf16x8*)(qrow + t * 16 + hi * 8);
    #pragma unroll
    for (int n = 0; n < 4; n++) O[n] = f32x16{};
  };

  auto do_tile = [&](int cur, int k0, int qw){
    const u16* Kc = Ks[cur];
    const u16* Vc = Vs[cur];
    f32x16 sc0 = {}, sc1 = {};
    const int krow0 = (l31 >> 1);
    const int kc0   = ((l31 & 1) << 4) | hi;
    __builtin_amdgcn_s_setprio(1);
    #pragma unroll
    for (int t = 0; t < 8; t++){
      bf16x8 ka0 = *(const bf16x8*)&Kc[krow0 * 256 + ((kc0 + 2 * t) ^ krow0) * 8];
      bf16x8 ka1 = *(const bf16x8*)&Kc[(16 + krow0) * 256 + ((kc0 + 2 * t) ^ (16 + krow0)) * 8];
      sc0 = __builtin_amdgcn_mfma_f32_32x32x16_bf16(ka0, qB[t], sc0, 0, 0, 0);
      sc1 = __builtin_amdgcn_mfma_f32_32x32x16_bf16(ka1, qB[t], sc1, 0, 0, 0);
    }
    __builtin_amdgcn_s_setprio(0);

    if (k0 + 63 > qw){
      const int qg = qw + l31;
      #pragma unroll
      for (int r = 0; r < 16; r++){
        int keyr = k0 + (r & 3) + 8 * (r >> 2) + 4 * hi;
        if (keyr      > qg) sc0[r] = -1e30f;
        if (keyr + 32 > qg) sc1[r] = -1e30f;
      }
    }
    float mx = sc0[0];
    #pragma unroll
    for (int r = 1; r < 16; r++) mx = fmaxf(mx, sc0[r]);
    #pragma unroll
    for (int r = 0; r < 16; r++) mx = fmaxf(mx, sc1[r]);
    mx = fmaxf(mx, __shfl_xor(mx, 32));
    if (!__all(mx <= m + RESCALE_THR2)){
      float mn = fmaxf(m, mx);
      float sf = exp2f(m - mn);
      m = mn;
      #pragma unroll
      for (int n = 0; n < 4; n++)
        #pragma unroll
        for (int r = 0; r < 16; r++) O[n][r] *= sf;
      Ll *= sf;
    }
    float p0[16], p1[16];
    #pragma unroll
    for (int r = 0; r < 16; r++){ p0[r] = exp2f(sc0[r] - m); Ll += p0[r]; }
    #pragma unroll
    for (int r = 0; r < 16; r++){ p1[r] = exp2f(sc1[r] - m); Ll += p1[r]; }

    __builtin_amdgcn_s_setprio(1);
    #pragma unroll
    for (int c = 0; c < 4; c++){
      const float* ps = (c & 2) ? p1 : p0;
      const int bb = (c & 1) * 8;
      u32 wa = cvtpk(ps[bb + 0], ps[bb + 1]);
      u32 wb = cvtpk(ps[bb + 2], ps[bb + 3]);
      u32 wc = cvtpk(ps[bb + 4], ps[bb + 5]);
      u32 wd = cvtpk(ps[bb + 6], ps[bb + 7]);
      asm("v_permlane32_swap_b32 %0, %1" : "+v"(wa), "+v"(wc));
      asm("v_permlane32_swap_b32 %0, %1" : "+v"(wb), "+v"(wd));
      u32x4 wv_; wv_[0] = wa; wv_[1] = wb; wv_[2] = wc; wv_[3] = wd;
      bf16x8 pf = __builtin_bit_cast(bf16x8, wv_);
      #pragma unroll
      for (int n = 0; n < 4; n++){
        const int vrow = n * 8 + (l31 >> 2);
        const int vcc  = ((l31 & 3) << 3) | (c << 1) | hi;
        bf16x8 va = *(const bf16x8*)&Vc[vrow * 256 + (vcc ^ vrow) * 8];
        O[n] = __builtin_amdgcn_mfma_f32_32x32x16_bf16(va, pf, O[n], 0, 0, 0);
      }
    }
    __builtin_amdgcn_s_setprio(0);
  };

  // run tiles [kt0, kt1) of stripe at q0; buffers start at cur=0
  auto run = [&](int q0, int kt0, int kt1){
    const int qw = q0 + w * 32;
    stage(0, kt0);
    __syncthreads();
    int cur = 0;
    for (int kt = kt0; kt < kt1; kt++){
      if (kt + 1 < kt1) stage(cur ^ 1, kt + 1);
      if (kt * 64 < qw + 32) do_tile(cur, kt * 64, qw);
      __syncthreads();
      cur ^= 1;
    }
  };

  // epilogue: transpose O via dead K buffers; final -> AO, else -> PART+lse
  auto epilogue = [&](int q0, bool final_, int rr_){
    float l = Ll + __shfl_xor(Ll, 32);
    float inv, lse;
    if (l > 0.f){ inv = 1.f / l; lse = m + __log2f(l); }
    else        { inv = 0.f;     lse = -1e30f; }
    u16* arena = &Ks[0][0];                // 32KB (both K buffers, dead)
    #pragma unroll
    for (int n = 0; n < 4; n++)
      #pragma unroll
      for (int r = 0; r < 16; r++){
        int vd = n * 32 + (r & 3) + 8 * (r >> 2) + 4 * hi;
        int ch = (vd >> 3) ^ (l31 & 15);
        arena[w * 4096 + l31 * 128 + ch * 8 + (vd & 7)] = f2bf(O[n][r] * inv);
      }
    __syncthreads();
    if (final_){
      #pragma unroll
      for (int pp = 0; pp < 8; pp++){
        int idx = pp * 256 + tid;
        int row = idx >> 4, c = idx & 15;
        u16x8 v = *(const u16x8*)&arena[row * 128 + ((c ^ (row & 15)) * 8)];
        *(u16x8*)&AO[(size_t)(q0 + row) * AOST + head * HD + c * 8] = v;
      }
    } else {
      u16* base = PART + (size_t)((head * 8 + p) * 2 + rr_) * PARTSZ;
      #pragma unroll
      for (int pp = 0; pp < 8; pp++){
        int idx = pp * 256 + tid;
        int row = idx >> 4, c = idx & 15;
        u16x8 v = *(const u16x8*)&arena[row * 128 + ((c ^ (row & 15)) * 8)];
        *(u16x8*)&base[row * 128 + c * 8] = v;
      }
      if (hi == 0) ((float*)(base + 16384))[w * 32 + l31] = lse;
    }
    __syncthreads();                       // arena reads done before next stage
  };

  const int q0L = qtL * 128;
  if (role == 0){
    // role A: long stripe, tiles [0, 18), sink in init
    load_q(q0L);
    m = sb2; Ll = (hi == 0) ? 1.f : 0.f;
    run(q0L, 0, 18);
    epilogue(q0L, false, 0);
  } else {
    // role B phase 1: long stripe, tiles [18, 32-2p), no sink
    load_q(q0L);
    m = -3.0e38f; Ll = 0.f;
    run(q0L, 18, 32 - 2 * p);
    epilogue(q0L, false, 1);
    // role B phase 2: short stripe p, all 2p+2 tiles, sink in init
    const int q0S = p * 128;
    load_q(q0S);
    m = sb2; Ll = (hi == 0) ? 1.f : 0.f;
    run(q0S, 0, 2 * p + 2);
    epilogue(q0S, true, 0);
  }
}

// ---------------- merge partials: AO[long stripe] = lse-weighted combine ---
__global__ void merge_kernel(const u16* __restrict__ PART, u16* __restrict__ AO){
  const int sidx = blockIdx.x;             // head*8 + p
  const int h = sidx >> 3, p = sidx & 7;
  const int q0 = (15 - p) * 128;
  const u16* A = PART + (size_t)(sidx * 2 + 0) * PARTSZ;
  const u16* B = PART + (size_t)(sidx * 2 + 1) * PARTSZ;
  const float* lseA = (const float*)(A + 16384);
  const float* lseB = (const float*)(B + 16384);
  #pragma unroll
  for (int it = 0; it < 8; it++){
    int idx = it * 256 + threadIdx.x;      // 2048 chunks: row(128) x c(16)
    int row = idx >> 4, c = (idx & 15) * 8;
    float la = lseA[row], lb = lseB[row];
    float mx = fmaxf(la, lb);
    float wa = exp2f(la - mx), wb = exp2f(lb - mx);
    float inv = 1.f / (wa + wb);
    u16x8 va = *(const u16x8*)&A[row * 128 + c];
    u16x8 vb = *(const u16x8*)&B[row * 128 + c];
    u16x8 o;
    #pragma unroll
    for (int j = 0; j < 8; j++)
      o[j] = f2bf((bf2f(va[j]) * wa + bf2f(vb[j]) * wb) * inv);
    *(u16x8*)&AO[(size_t)(q0 + row) * AOST + h * HD + c] = o;
  }
}

// ---------------- host-side launch ----------------
extern "C" void kernel_launch(void* const* d_in, const int* in_sizes, int n_in,
                              void* d_out, int out_size, void* d_ws, size_t ws_size,
                              hipStream_t stream){
  (void)in_sizes; (void)n_in; (void)out_size; (void)ws_size;
  const float* hs    = (const float*)d_in[0];
  const float* cosv  = (const float*)d_in[1];
  const float* sinv  = (const float*)d_in[2];
  /* d_in[3] attention_mask: pure causal triu(NEG,1) - implemented directly */
  const float* Wq    = (const float*)d_in[4];
  const float* Wk    = (const float*)d_in[5];
  const float* Wv    = (const float*)d_in[6];
  const float* Wo    = (const float*)d_in[7];
  const float* sinkb = (const float*)d_in[8];
  float* out = (float*)d_out;

  char* ws = (char*)d_ws;
  u16* XB    = (u16*)(ws);                  //  8,388,608  X bf16 [2048][2048]
  u16* WQKVB = (u16*)(ws + 8388608);        // 25,165,824  Wqkv bf16 [6144][2048]
  u16* WOB   = (u16*)(ws + 33554432);       // 16,777,216  Wo bf16 [2048][4096]
  u16* QKV   = (u16*)(ws + 50331648);       // 25,165,824  QKV bf16 [2048][6144]
  u16* VT    = (u16*)(ws + 75497472);       //  4,194,304  V^T bf16 [8][128][2048]
  u16* AO    = (u16*)(ws + 79691776);       // 16,777,216  attn out bf16 [2048][4096]
  u16* PART  = (u16*)(ws);                  // 17,039,360  partials (XB region,
                                            //   dead after the QKV GEMM)

  cvt_all_kernel<<<24576, 256, 0, stream>>>((const f32x4*)hs, (const f32x4*)Wq,
                                            (const f32x4*)Wk, (const f32x4*)Wv,
                                            (const f32x4*)Wo, (u16x4*)ws);

  // fused QKV projection + RoPE + Q-scale(log2e): m97 geometry (128/128/32)
  gemm_bt_kernel<1, 1, 128, 128, 32><<<dim3(48, 16), 256, 0, stream>>>(XB, WQKVB, QKV, 2048, 6144, 2048, cosv, sinv);

  vtrans_kernel<<<8192, 256, 0, stream>>>(QKV, VT);

  // attention: 512 blocks, balanced 18/16-tile roles (A: b<256, B: b>=256)
  attn_kernel<<<dim3(512), 256, 0, stream>>>(QKV, VT, sinkb, AO, PART);

  // merge split (long) stripes: 256 stripes, lse-weighted combine
  merge_kernel<<<dim3(256), 256, 0, stream>>>(PART, AO);

  // output projection (f32 out): 128/64/64, 16 MFMA/barrier
  gemm_bt_kernel<0, 0, 128, 64, 64><<<dim3(32, 16), 256, 0, stream>>>(AO, WOB, out, 2048, 2048, 4096, nullptr, nullptr);
}

// Round 21
// 214.593 us; speedup vs baseline: 1.0999x; 1.0250x over previous
//
#include <hip/hip_runtime.h>

typedef unsigned short u16;
typedef unsigned int   u32;
typedef __bf16  bf16x8 __attribute__((ext_vector_type(8)));
typedef float   f32x4  __attribute__((ext_vector_type(4)));
typedef float   f32x16 __attribute__((ext_vector_type(16)));
typedef u16     u16x4  __attribute__((ext_vector_type(4)));
typedef u16     u16x8  __attribute__((ext_vector_type(8)));
typedef u32     u32x4  __attribute__((ext_vector_type(4)));

#define S_LEN 2048
#define NH 32
#define NKVH 8
#define HD 128
#define QKVST 6144          /* packed QKV row stride  */
#define AOST  4096          /* attn-out row stride    */
#define ATT_SCALE 0.08838834764831845f
#define LOG2E 1.4426950408889634f
#define QSC2 (ATT_SCALE * LOG2E)
#define RESCALE_THR2 11.5f
#define PARTSZ 33280        /* u16 per record: 256x128 bf16 O + 256 f32 lse */

__device__ __forceinline__ u16 f2bf(float f){
  u32 u = __builtin_bit_cast(u32, f);
  u += 0x7FFFu + ((u >> 16) & 1u);
  return (u16)(u >> 16);
}
__device__ __forceinline__ float bf2f(u16 h){
  u32 u = ((u32)h) << 16;
  return __builtin_bit_cast(float, u);
}
__device__ __forceinline__ u32 cvtpk(float lo, float hi){
  u32 d;
  asm("v_cvt_pk_bf16_f32 %0, %1, %2" : "=v"(d) : "v"(lo), "v"(hi));
  return d;
}
// async global->LDS, 16B per lane. Dest must be wave-uniform base + lane*16.
__device__ __forceinline__ void gload_lds16(const u16* g, u16* l){
  __builtin_amdgcn_global_load_lds(
      (const __attribute__((address_space(1))) void*)g,
      (__attribute__((address_space(3))) void*)l, 16, 0, 0);
}

// ------------- fused f32 -> bf16 convert of ALL inputs (one launch) --------
__global__ void cvt_all_kernel(const f32x4* __restrict__ hs, const f32x4* __restrict__ wq,
                               const f32x4* __restrict__ wk, const f32x4* __restrict__ wv,
                               const f32x4* __restrict__ wo, u16x4* __restrict__ out){
  int i = blockIdx.x * 256 + threadIdx.x;          // 0 .. 6291455
  const f32x4* src; int off;
  if      (i < 1048576){ src = hs; off = i; }
  else if (i < 3145728){ src = wq; off = i - 1048576; }
  else if (i < 3670016){ src = wk; off = i - 3145728; }
  else if (i < 4194304){ src = wv; off = i - 3670016; }
  else                 { src = wo; off = i - 4194304; }
  f32x4 v = src[off];
  u16x4 o;
  o[0] = f2bf(v[0]); o[1] = f2bf(v[1]); o[2] = f2bf(v[2]); o[3] = f2bf(v[3]);
  out[i] = o;
}

// ---------------- GEMM: C[M][N] = X[M][K] @ W[N][K]^T (bf16 in, f32 acc) ----
// QKV: 128/128/32. O-proj: 128/64/64. Both >=16 MFMA/barrier. Both-sides LDS
// XOR swizzle (R20, verified +3.4us): chunk' = chunk ^ ((row>>1)&3), applied
// to the pre-swizzled global source (linear LDS dest) and the read.
template<int OUT_BF16, int ROPE, int BM, int BN, int BK>
__global__ __launch_bounds__(256, 2)
void gemm_bt_kernel(const u16* __restrict__ X, const u16* __restrict__ W,
                    void* __restrict__ Cv, int M, int N, int K,
                    const float* __restrict__ cosv, const float* __restrict__ sinv){
  const int NS = BK / 32;
  __shared__ __align__(16) u16 As[2][NS][BM * 32];
  __shared__ __align__(16) u16 Bs[2][NS][BN * 32];
  const int MI = BM / 32, NJ = BN / 32;
  const int m0 = blockIdx.y * BM, n0 = blockIdx.x * BN;
  const int tid = threadIdx.x;
  const int wave = tid >> 6, lane = tid & 63;
  const int wm = wave >> 1, wn = wave & 1;
  const int g = lane >> 4, ln = lane & 15;
  const int r0 = tid >> 2;
  const int cc = (((tid & 3) ^ ((r0 >> 1) & 3)) * 8);
  f32x4 acc[MI][NJ] = {};
  const u16* xa0 = X + (size_t)(m0 + r0) * K + cc;
  const u16* xa1 = X + (size_t)(m0 + r0 + 64) * K + (((tid & 3) ^ (((r0 + 64) >> 1) & 3)) * 8);
  const u16* wb0 = W + (size_t)(n0 + r0) * K + cc;
  const u16* wb1 = W + (size_t)(n0 + r0 + 64) * K + (((tid & 3) ^ (((r0 + 64) >> 1) & 3)) * 8);

  auto stage = [&](int buf, int k0){
    #pragma unroll
    for (int s = 0; s < NS; s++){
      const int kc = k0 + s * 32;
      gload_lds16(xa0 + kc, &As[buf][s][tid * 8]);
      if (BM == 128) gload_lds16(xa1 + kc, &As[buf][s][2048 + tid * 8]);
      gload_lds16(wb0 + kc, &Bs[buf][s][tid * 8]);
      if (BN == 128) gload_lds16(wb1 + kc, &Bs[buf][s][2048 + tid * 8]);
    }
  };

  stage(0, 0);
  __syncthreads();
  int cur = 0;
  for (int k0 = 0; k0 < K; k0 += BK){
    if (k0 + BK < K) stage(cur ^ 1, k0 + BK);
    #pragma unroll
    for (int s = 0; s < NS; s++){
      bf16x8 a[MI], b[NJ];
      #pragma unroll
      for (int f = 0; f < MI; f++){
        const int row = wm * (BM / 2) + f * 16 + ln;
        a[f] = *(const bf16x8*)&As[cur][s][row * 32 + ((g ^ ((row >> 1) & 3)) * 8)];
      }
      #pragma unroll
      for (int f = 0; f < NJ; f++){
        const int row = wn * (BN / 2) + f * 16 + ln;
        b[f] = *(const bf16x8*)&Bs[cur][s][row * 32 + ((g ^ ((row >> 1) & 3)) * 8)];
      }
      __builtin_amdgcn_s_setprio(1);
      #pragma unroll
      for (int i = 0; i < MI; i++)
        #pragma unroll
        for (int j = 0; j < NJ; j++)
          acc[i][j] = __builtin_amdgcn_mfma_f32_16x16x32_bf16(a[i], b[j], acc[i][j], 0, 0, 0);
      __builtin_amdgcn_s_setprio(0);
    }
    __syncthreads();
    cur ^= 1;
  }
  if (ROPE && BN == 128){
    if (wn == 0 && n0 < 5120){
      #pragma unroll
      for (int i = 0; i < MI; i++)
        #pragma unroll
        for (int r = 0; r < 4; r++){
          const int row = m0 + wm * (BM / 2) + i * 16 + g * 4 + r;
          #pragma unroll
          for (int j = 0; j < 2; j++){
            const int d = j * 16 + ln;
            float c  = cosv[row * 64 + d];
            float sn = sinv[row * 64 + d];
            float x0 = acc[i][j][r], x1 = acc[i][j + 2][r];
            acc[i][j][r]     = x0 * c - x1 * sn;
            acc[i][j + 2][r] = x1 * c + x0 * sn;
          }
        }
    }
    if (n0 < 4096){
      #pragma unroll
      for (int i = 0; i < MI; i++)
        #pragma unroll
        for (int j = 0; j < NJ; j++)
          #pragma unroll
          for (int r = 0; r < 4; r++) acc[i][j][r] *= QSC2;
    }
  }
  #pragma unroll
  for (int i = 0; i < MI; i++)
    #pragma unroll
    for (int j = 0; j < NJ; j++)
      #pragma unroll
      for (int r = 0; r < 4; r++){
        int row = m0 + wm * (BM / 2) + i * 16 + g * 4 + r;
        int col = n0 + wn * (BN / 2) + j * 16 + ln;
        if (OUT_BF16) ((u16*)Cv)[(size_t)row * N + col] = f2bf(acc[i][j][r]);
        else          ((float*)Cv)[(size_t)row * N + col] = acc[i][j][r];
      }
}

// ---------------- V transpose: VT[kvh][vd][s] from packed QKV -------------
__global__ void vtrans_kernel(const u16* __restrict__ QKV, u16* __restrict__ VT){
  int idx = blockIdx.x * 256 + threadIdx.x;
  if (idx >= NKVH * HD * S_LEN) return;
  int s   = idx & (S_LEN - 1);
  int vd  = (idx >> 11) & (HD - 1);
  int kvh = idx >> 18;
  VT[idx] = QKV[(size_t)s * QKVST + 5120 + kvh * HD + vd];
}

// --------- causal flash attention: 8-wave GQA-shared + stream-K split ------
// Combines R13's verified 8-wave body (4 heads x 2 halves share ONE K/V
// dbuf; measured 2.84us/8-wave-tile, ~17% cheaper than 2x4-wave) with
// R16/R19's uniform stream-K split (which fixes R13's imbalance).
// 64-row stripes qt in [0,32); pairs {31-s, s}. Role A = long stripe tiles
// [0,17) -> partial rec 0; role B = long [17,32-s) -> partial rec 1, then
// short stripe s (s+1 tiles) -> final. A=17+1epi, B=16+2epis (balanced).
// Grid = 8 kvh x 16 s x 2 roles = 256 blocks x 512 threads (1/CU, 8 waves).
// s=15: B phase 1 empty -> run() early-returns (no orphaned DMA vs arena).
__global__ __launch_bounds__(512, 2)
void attn_kernel(const u16* __restrict__ QKV, const u16* __restrict__ VT,
                 const float* __restrict__ sinkb, u16* __restrict__ AO,
                 u16* __restrict__ PART){
  __shared__ __align__(16) u16 lds[4][32 * 256];  // [K0,K1,V0,V1] 16KB each
  const int b    = blockIdx.x;
  const int kvh  = b & 7;                  // XCD-aligned kv-head
  const int s    = (b >> 3) & 15;          // pair index 0..15
  const int role = b >> 7;                 // 0 = A, 1 = B
  const int qtL  = 31 - s;
  const int tid  = threadIdx.x;
  const int w    = tid >> 6;               // 0..7: head (w>>1), q-half (w&1)
  const int head = kvh * 4 + (w >> 1);
  const int lane = tid & 63;
  const int l31  = lane & 31, hi = lane >> 5;

  const u16* Kbase = QKV + 4096 + kvh * HD;           // + row*QKVST
  const u16* Vbase = VT + (size_t)kvh * HD * S_LEN;   // + vd*S_LEN + key

  // stage tile kt (64 keys): 1024 K-chunks + 1024 V-chunks over 512 threads
  auto stage = [&](int buf, int kt){
    const int k0 = kt * 64;
    #pragma unroll
    for (int pp = 0; pp < 2; pp++){
      int idx = pp * 512 + tid;            // K: row r(32) x chunk c(32)
      int r = idx >> 5, c = idx & 31;
      int cs = c ^ r;
      int key = r * 2 + (cs >> 4), d8 = (cs & 15) * 8;
      gload_lds16(Kbase + (size_t)(k0 + key) * QKVST + d8, &lds[buf][idx * 8]);
    }
    #pragma unroll
    for (int pp = 0; pp < 2; pp++){
      int idx = pp * 512 + tid;            // V: row r(32) x chunk c(32)
      int r = idx >> 5, c = idx & 31;
      int cs = c ^ r;
      int vd = r * 4 + (cs >> 3), k8 = (cs & 7) * 8;
      gload_lds16(Vbase + (size_t)vd * S_LEN + k0 + k8, &lds[2 + buf][idx * 8]);
    }
  };

  const float sb2 = sinkb[head] * LOG2E;
  bf16x8 qB[8];
  float m, Ll;
  f32x16 O[4];

  auto load_q = [&](int q0){
    const int qw = q0 + (w & 1) * 32;
    const u16* qrow = QKV + (size_t)(qw + l31) * QKVST + head * HD;
    #pragma unroll
    for (int t = 0; t < 8; t++) qB[t] = *(const bf16x8*)(qrow + t * 16 + hi * 8);
    #pragma unroll
    for (int n = 0; n < 4; n++) O[n] = f32x16{};
  };

  auto do_tile = [&](int cur, int k0, int qw){
    const u16* Kc = lds[cur];
    const u16* Vc = lds[2 + cur];
    f32x16 sc0 = {}, sc1 = {};
    const int krow0 = (l31 >> 1);
    const int kc0   = ((l31 & 1) << 4) | hi;
    __builtin_amdgcn_s_setprio(1);
    #pragma unroll
    for (int t = 0; t < 8; t++){
      bf16x8 ka0 = *(const bf16x8*)&Kc[krow0 * 256 + ((kc0 + 2 * t) ^ krow0) * 8];
      bf16x8 ka1 = *(const bf16x8*)&Kc[(16 + krow0) * 256 + ((kc0 + 2 * t) ^ (16 + krow0)) * 8];
      sc0 = __builtin_amdgcn_mfma_f32_32x32x16_bf16(ka0, qB[t], sc0, 0, 0, 0);
      sc1 = __builtin_amdgcn_mfma_f32_32x32x16_bf16(ka1, qB[t], sc1, 0, 0, 0);
    }
    __builtin_amdgcn_s_setprio(0);

    if (k0 + 63 > qw){
      const int qg = qw + l31;
      #pragma unroll
      for (int r = 0; r < 16; r++){
        int keyr = k0 + (r & 3) + 8 * (r >> 2) + 4 * hi;
        if (keyr      > qg) sc0[r] = -1e30f;
        if (keyr + 32 > qg) sc1[r] = -1e30f;
      }
    }
    float mx = sc0[0];
    #pragma unroll
    for (int r = 1; r < 16; r++) mx = fmaxf(mx, sc0[r]);
    #pragma unroll
    for (int r = 0; r < 16; r++) mx = fmaxf(mx, sc1[r]);
    mx = fmaxf(mx, __shfl_xor(mx, 32));
    if (!__all(mx <= m + RESCALE_THR2)){
      float mn = fmaxf(m, mx);
      float sf = exp2f(m - mn);
      m = mn;
      #pragma unroll
      for (int n = 0; n < 4; n++)
        #pragma unroll
        for (int r = 0; r < 16; r++) O[n][r] *= sf;
      Ll *= sf;
    }
    float p0[16], p1[16];
    #pragma unroll
    for (int r = 0; r < 16; r++){ p0[r] = exp2f(sc0[r] - m); Ll += p0[r]; }
    #pragma unroll
    for (int r = 0; r < 16; r++){ p1[r] = exp2f(sc1[r] - m); Ll += p1[r]; }

    __builtin_amdgcn_s_setprio(1);
    #pragma unroll
    for (int c = 0; c < 4; c++){
      const float* ps = (c & 2) ? p1 : p0;
      const int bb = (c & 1) * 8;
      u32 wa = cvtpk(ps[bb + 0], ps[bb + 1]);
      u32 wb = cvtpk(ps[bb + 2], ps[bb + 3]);
      u32 wc = cvtpk(ps[bb + 4], ps[bb + 5]);
      u32 wd = cvtpk(ps[bb + 6], ps[bb + 7]);
      asm("v_permlane32_swap_b32 %0, %1" : "+v"(wa), "+v"(wc));
      asm("v_permlane32_swap_b32 %0, %1" : "+v"(wb), "+v"(wd));
      u32x4 wv_; wv_[0] = wa; wv_[1] = wb; wv_[2] = wc; wv_[3] = wd;
      bf16x8 pf = __builtin_bit_cast(bf16x8, wv_);
      #pragma unroll
      for (int n = 0; n < 4; n++){
        const int vrow = n * 8 + (l31 >> 2);
        const int vcc  = ((l31 & 3) << 3) | (c << 1) | hi;
        bf16x8 va = *(const bf16x8*)&Vc[vrow * 256 + (vcc ^ vrow) * 8];
        O[n] = __builtin_amdgcn_mfma_f32_32x32x16_bf16(va, pf, O[n], 0, 0, 0);
      }
    }
    __builtin_amdgcn_s_setprio(0);
  };

  // run tiles [kt0, kt1) of stripe at q0; no-op (and no DMA) when empty
  auto run = [&](int q0, int kt0, int kt1){
    if (kt0 >= kt1) return;
    const int qw = q0 + (w & 1) * 32;
    stage(0, kt0);
    __syncthreads();
    int cur = 0;
    for (int kt = kt0; kt < kt1; kt++){
      if (kt + 1 < kt1) stage(cur ^ 1, kt + 1);
      if (kt * 64 < qw + 32) do_tile(cur, kt * 64, qw);
      __syncthreads();
      cur ^= 1;
    }
  };

  // epilogue: transpose O via the whole 64KB LDS (all buffers dead here).
  // arena row rr = w*32+l31 -> head = kvh*4 + (rr>>6), qrow = q0 + (rr&63).
  auto epilogue = [&](int q0, bool final_, int rec){
    float l = Ll + __shfl_xor(Ll, 32);
    float inv, lse;
    if (l > 0.f){ inv = 1.f / l; lse = m + __log2f(l); }
    else        { inv = 0.f;     lse = -1e30f; }
    u16* arena = &lds[0][0];               // 256 rows x 256B = 64KB
    const int rr = w * 32 + l31;
    #pragma unroll
    for (int n = 0; n < 4; n++)
      #pragma unroll
      for (int r = 0; r < 16; r++){
        int vd = n * 32 + (r & 3) + 8 * (r >> 2) + 4 * hi;
        int ch = (vd >> 3) ^ (l31 & 15);
        arena[rr * 128 + ch * 8 + (vd & 7)] = f2bf(O[n][r] * inv);
      }
    __syncthreads();
    if (final_){
      #pragma unroll
      for (int pp = 0; pp < 8; pp++){
        int idx = pp * 512 + tid;          // 4096 chunks: row(256) x c(16)
        int row = idx >> 4, c = idx & 15;
        u16x8 v = *(const u16x8*)&arena[row * 128 + ((c ^ (row & 15)) * 8)];
        *(u16x8*)&AO[(size_t)(q0 + (row & 63)) * AOST + (kvh * 4 + (row >> 6)) * HD + c * 8] = v;
      }
    } else {
      u16* base = PART + (size_t)((kvh * 16 + s) * 2 + rec) * PARTSZ;
      #pragma unroll
      for (int pp = 0; pp < 8; pp++){
        int idx = pp * 512 + tid;
        int row = idx >> 4, c = idx & 15;
        u16x8 v = *(const u16x8*)&arena[row * 128 + ((c ^ (row & 15)) * 8)];
        *(u16x8*)&base[row * 128 + c * 8] = v;
      }
      if (hi == 0) ((float*)(base + 32768))[rr] = lse;
    }
    __syncthreads();                       // arena reads done before next stage
  };

  const int q0L = qtL * 64;
  if (role == 0){
    // role A: long stripe, tiles [0, 17), sink in init
    load_q(q0L);
    m = sb2; Ll = (hi == 0) ? 1.f : 0.f;
    run(q0L, 0, 17);
    epilogue(q0L, false, 0);
  } else {
    // role B phase 1: long stripe, tiles [17, 32-s), no sink
    load_q(q0L);
    m = -3.0e38f; Ll = 0.f;
    run(q0L, 17, 32 - s);
    epilogue(q0L, false, 1);
    // role B phase 2: short stripe s, tiles [0, s+1), sink in init
    const int q0S = s * 64;
    load_q(q0S);
    m = sb2; Ll = (hi == 0) ? 1.f : 0.f;
    run(q0S, 0, s + 1);
    epilogue(q0S, true, 0);
  }
}

// ---------------- merge partials: AO[long stripe] = lse-weighted combine ---
// 128 records-pairs (kvh x s); record rows decode as in attn epilogue.
__global__ void merge_kernel(const u16* __restrict__ PART, u16* __restrict__ AO){
  const int sidx = blockIdx.x;             // kvh*16 + s
  const int kvh = sidx >> 4, s = sidx & 15;
  const int q0 = (31 - s) * 64;
  const u16* A = PART + (size_t)(sidx * 2 + 0) * PARTSZ;
  const u16* B = PART + (size_t)(sidx * 2 + 1) * PARTSZ;
  const float* lseA = (const float*)(A + 32768);
  const float* lseB = (const float*)(B + 32768);
  #pragma unroll
  for (int it = 0; it < 16; it++){
    int idx = it * 256 + threadIdx.x;      // 4096 chunks: row(256) x c(16)
    int row = idx >> 4, c = (idx & 15) * 8;
    float la = lseA[row], lb = lseB[row];
    float mx = fmaxf(la, lb);
    float wa = exp2f(la - mx), wb = exp2f(lb - mx);
    float inv = 1.f / (wa + wb);
    u16x8 va = *(const u16x8*)&A[row * 128 + c];
    u16x8 vb = *(const u16x8*)&B[row * 128 + c];
    u16x8 o;
    #pragma unroll
    for (int j = 0; j < 8; j++)
      o[j] = f2bf((bf2f(va[j]) * wa + bf2f(vb[j]) * wb) * inv);
    *(u16x8*)&AO[(size_t)(q0 + (row & 63)) * AOST + (kvh * 4 + (row >> 6)) * HD + c] = o;
  }
}

// ---------------- host-side launch ----------------
extern "C" void kernel_launch(void* const* d_in, const int* in_sizes, int n_in,
                              void* d_out, int out_size, void* d_ws, size_t ws_size,
                              hipStream_t stream){
  (void)in_sizes; (void)n_in; (void)out_size; (void)ws_size;
  const float* hs    = (const float*)d_in[0];
  const float* cosv  = (const float*)d_in[1];
  const float* sinv  = (const float*)d_in[2];
  /* d_in[3] attention_mask: pure causal triu(NEG,1) - implemented directly */
  const float* Wq    = (const float*)d_in[4];
  const float* Wk    = (const float*)d_in[5];
  const float* Wv    = (const float*)d_in[6];
  const float* Wo    = (const float*)d_in[7];
  const float* sinkb = (const float*)d_in[8];
  float* out = (float*)d_out;

  char* ws = (char*)d_ws;
  u16* XB    = (u16*)(ws);                  //  8,388,608  X bf16 [2048][2048]
  u16* WQKVB = (u16*)(ws + 8388608);        // 25,165,824  Wqkv bf16 [6144][2048]
  u16* WOB   = (u16*)(ws + 33554432);       // 16,777,216  Wo bf16 [2048][4096]
  u16* QKV   = (u16*)(ws + 50331648);       // 25,165,824  QKV bf16 [2048][6144]
  u16* VT    = (u16*)(ws + 75497472);       //  4,194,304  V^T bf16 [8][128][2048]
  u16* AO    = (u16*)(ws + 79691776);       // 16,777,216  attn out bf16 [2048][4096]
  u16* PART  = (u16*)(ws);                  // 17,039,360  partials (XB+WQKVB
                                            //   region, dead after QKV GEMM)

  cvt_all_kernel<<<24576, 256, 0, stream>>>((const f32x4*)hs, (const f32x4*)Wq,
                                            (const f32x4*)Wk, (const f32x4*)Wv,
                                            (const f32x4*)Wo, (u16x4*)ws);

  // fused QKV projection + RoPE + Q-scale(log2e): m97 geometry (128/128/32)
  gemm_bt_kernel<1, 1, 128, 128, 32><<<dim3(48, 16), 256, 0, stream>>>(XB, WQKVB, QKV, 2048, 6144, 2048, cosv, sinv);

  vtrans_kernel<<<8192, 256, 0, stream>>>(QKV, VT);

  // attention: 256 blocks x 512 threads (8-wave GQA-shared, stream-K 17/16)
  attn_kernel<<<dim3(256), 512, 0, stream>>>(QKV, VT, sinkb, AO, PART);

  // merge split (long) stripes: 128 record-pairs, lse-weighted combine
  merge_kernel<<<dim3(128), 256, 0, stream>>>(PART, AO);

  // output projection (f32 out): 128/64/64, 16 MFMA/barrier
  gemm_bt_kernel<0, 0, 128, 64, 64><<<dim3(32, 16), 256, 0, stream>>>(AO, WOB, out, 2048, 2048, 4096, nullptr, nullptr);
}

// Round 22
// 210.849 us; speedup vs baseline: 1.1195x; 1.0178x over previous
//
#include <hip/hip_runtime.h>

typedef unsigned short u16;
typedef unsigned int   u32;
typedef __bf16  bf16x8 __attribute__((ext_vector_type(8)));
typedef float   f32x4  __attribute__((ext_vector_type(4)));
typedef float   f32x16 __attribute__((ext_vector_type(16)));
typedef u16     u16x4  __attribute__((ext_vector_type(4)));
typedef u16     u16x8  __attribute__((ext_vector_type(8)));
typedef u32     u32x4  __attribute__((ext_vector_type(4)));

#define S_LEN 2048
#define NH 32
#define NKVH 8
#define HD 128
#define QKVST 6144          /* packed QKV row stride  */
#define AOST  4096          /* attn-out row stride    */
#define ATT_SCALE 0.08838834764831845f
#define LOG2E 1.4426950408889634f
#define QSC2 (ATT_SCALE * LOG2E)
#define RESCALE_THR2 11.5f
#define PARTSZ 33280        /* u16 per record: 256x128 bf16 O + 256 f32 lse */

__device__ __forceinline__ u16 f2bf(float f){
  u32 u = __builtin_bit_cast(u32, f);
  u += 0x7FFFu + ((u >> 16) & 1u);
  return (u16)(u >> 16);
}
__device__ __forceinline__ float bf2f(u16 h){
  u32 u = ((u32)h) << 16;
  return __builtin_bit_cast(float, u);
}
__device__ __forceinline__ u32 cvtpk(float lo, float hi){
  u32 d;
  asm("v_cvt_pk_bf16_f32 %0, %1, %2" : "=v"(d) : "v"(lo), "v"(hi));
  return d;
}
// async global->LDS, 16B per lane. Dest must be wave-uniform base + lane*16.
__device__ __forceinline__ void gload_lds16(const u16* g, u16* l){
  __builtin_amdgcn_global_load_lds(
      (const __attribute__((address_space(1))) void*)g,
      (__attribute__((address_space(3))) void*)l, 16, 0, 0);
}

// ------------- fused f32 -> bf16 convert of ALL inputs (one launch) --------
// 8 f32 -> u16x8 (16B store) per thread; segment sizes are all x8-aligned.
__global__ void cvt_all_kernel(const f32x4* __restrict__ hs, const f32x4* __restrict__ wq,
                               const f32x4* __restrict__ wk, const f32x4* __restrict__ wv,
                               const f32x4* __restrict__ wo, u16x8* __restrict__ out){
  int i = blockIdx.x * 256 + threadIdx.x;          // 0 .. 3145727 (x8 chunks)
  const f32x4* src; int off;                       // off in f32x4 units
  if      (i <  524288){ src = hs; off = i * 2; }
  else if (i < 1572864){ src = wq; off = (i -  524288) * 2; }
  else if (i < 1835008){ src = wk; off = (i - 1572864) * 2; }
  else if (i < 2097152){ src = wv; off = (i - 1835008) * 2; }
  else                 { src = wo; off = (i - 2097152) * 2; }
  f32x4 a = src[off], b = src[off + 1];
  u16x8 o;
  o[0] = f2bf(a[0]); o[1] = f2bf(a[1]); o[2] = f2bf(a[2]); o[3] = f2bf(a[3]);
  o[4] = f2bf(b[0]); o[5] = f2bf(b[1]); o[6] = f2bf(b[2]); o[7] = f2bf(b[3]);
  out[i] = o;
}

// ---------------- GEMM: C[M][N] = X[M][K] @ W[N][K]^T (bf16 in, f32 acc) ----
// QKV: 128/128/32. O-proj: 128/64/64. Both >=16 MFMA/barrier. Both-sides LDS
// XOR swizzle (R20): chunk' = chunk ^ ((row>>1)&3), applied to the
// pre-swizzled global source (linear LDS dest) and the read.
template<int OUT_BF16, int ROPE, int BM, int BN, int BK>
__global__ __launch_bounds__(256, 2)
void gemm_bt_kernel(const u16* __restrict__ X, const u16* __restrict__ W,
                    void* __restrict__ Cv, int M, int N, int K,
                    const float* __restrict__ cosv, const float* __restrict__ sinv){
  const int NS = BK / 32;
  __shared__ __align__(16) u16 As[2][NS][BM * 32];
  __shared__ __align__(16) u16 Bs[2][NS][BN * 32];
  const int MI = BM / 32, NJ = BN / 32;
  const int m0 = blockIdx.y * BM, n0 = blockIdx.x * BN;
  const int tid = threadIdx.x;
  const int wave = tid >> 6, lane = tid & 63;
  const int wm = wave >> 1, wn = wave & 1;
  const int g = lane >> 4, ln = lane & 15;
  const int r0 = tid >> 2;
  const int cc = (((tid & 3) ^ ((r0 >> 1) & 3)) * 8);
  f32x4 acc[MI][NJ] = {};
  const u16* xa0 = X + (size_t)(m0 + r0) * K + cc;
  const u16* xa1 = X + (size_t)(m0 + r0 + 64) * K + (((tid & 3) ^ (((r0 + 64) >> 1) & 3)) * 8);
  const u16* wb0 = W + (size_t)(n0 + r0) * K + cc;
  const u16* wb1 = W + (size_t)(n0 + r0 + 64) * K + (((tid & 3) ^ (((r0 + 64) >> 1) & 3)) * 8);

  auto stage = [&](int buf, int k0){
    #pragma unroll
    for (int s = 0; s < NS; s++){
      const int kc = k0 + s * 32;
      gload_lds16(xa0 + kc, &As[buf][s][tid * 8]);
      if (BM == 128) gload_lds16(xa1 + kc, &As[buf][s][2048 + tid * 8]);
      gload_lds16(wb0 + kc, &Bs[buf][s][tid * 8]);
      if (BN == 128) gload_lds16(wb1 + kc, &Bs[buf][s][2048 + tid * 8]);
    }
  };

  stage(0, 0);
  __syncthreads();
  int cur = 0;
  for (int k0 = 0; k0 < K; k0 += BK){
    if (k0 + BK < K) stage(cur ^ 1, k0 + BK);
    #pragma unroll
    for (int s = 0; s < NS; s++){
      bf16x8 a[MI], b[NJ];
      #pragma unroll
      for (int f = 0; f < MI; f++){
        const int row = wm * (BM / 2) + f * 16 + ln;
        a[f] = *(const bf16x8*)&As[cur][s][row * 32 + ((g ^ ((row >> 1) & 3)) * 8)];
      }
      #pragma unroll
      for (int f = 0; f < NJ; f++){
        const int row = wn * (BN / 2) + f * 16 + ln;
        b[f] = *(const bf16x8*)&Bs[cur][s][row * 32 + ((g ^ ((row >> 1) & 3)) * 8)];
      }
      __builtin_amdgcn_s_setprio(1);
      #pragma unroll
      for (int i = 0; i < MI; i++)
        #pragma unroll
        for (int j = 0; j < NJ; j++)
          acc[i][j] = __builtin_amdgcn_mfma_f32_16x16x32_bf16(a[i], b[j], acc[i][j], 0, 0, 0);
      __builtin_amdgcn_s_setprio(0);
    }
    __syncthreads();
    cur ^= 1;
  }
  if (ROPE && BN == 128){
    if (wn == 0 && n0 < 5120){
      #pragma unroll
      for (int i = 0; i < MI; i++)
        #pragma unroll
        for (int r = 0; r < 4; r++){
          const int row = m0 + wm * (BM / 2) + i * 16 + g * 4 + r;
          #pragma unroll
          for (int j = 0; j < 2; j++){
            const int d = j * 16 + ln;
            float c  = cosv[row * 64 + d];
            float sn = sinv[row * 64 + d];
            float x0 = acc[i][j][r], x1 = acc[i][j + 2][r];
            acc[i][j][r]     = x0 * c - x1 * sn;
            acc[i][j + 2][r] = x1 * c + x0 * sn;
          }
        }
    }
    if (n0 < 4096){
      #pragma unroll
      for (int i = 0; i < MI; i++)
        #pragma unroll
        for (int j = 0; j < NJ; j++)
          #pragma unroll
          for (int r = 0; r < 4; r++) acc[i][j][r] *= QSC2;
    }
  }
  #pragma unroll
  for (int i = 0; i < MI; i++)
    #pragma unroll
    for (int j = 0; j < NJ; j++)
      #pragma unroll
      for (int r = 0; r < 4; r++){
        int row = m0 + wm * (BM / 2) + i * 16 + g * 4 + r;
        int col = n0 + wn * (BN / 2) + j * 16 + ln;
        if (OUT_BF16) ((u16*)Cv)[(size_t)row * N + col] = f2bf(acc[i][j][r]);
        else          ((float*)Cv)[(size_t)row * N + col] = acc[i][j][r];
      }
}

// ---------------- V transpose: VT[kvh][vd][s] from packed QKV -------------
__global__ void vtrans_kernel(const u16* __restrict__ QKV, u16* __restrict__ VT){
  int idx = blockIdx.x * 256 + threadIdx.x;
  if (idx >= NKVH * HD * S_LEN) return;
  int s   = idx & (S_LEN - 1);
  int vd  = (idx >> 11) & (HD - 1);
  int kvh = idx >> 18;
  VT[idx] = QKV[(size_t)s * QKVST + 5120 + kvh * HD + vd];
}

// --------- causal flash attention: 8-wave GQA-shared + stream-K split ------
// (R21 verbatim — verified best. 64-row stripes qt in [0,32); pairs {31-s,s}.
// Role A = long stripe tiles [0,17) -> partial rec 0; role B = long
// [17,32-s) -> partial rec 1, then short stripe s (s+1 tiles) -> final.
// 256 blocks x 512 threads; 4 heads x 2 halves share one K/V dbuf.)
__global__ __launch_bounds__(512, 2)
void attn_kernel(const u16* __restrict__ QKV, const u16* __restrict__ VT,
                 const float* __restrict__ sinkb, u16* __restrict__ AO,
                 u16* __restrict__ PART){
  __shared__ __align__(16) u16 lds[4][32 * 256];  // [K0,K1,V0,V1] 16KB each
  const int b    = blockIdx.x;
  const int kvh  = b & 7;                  // XCD-aligned kv-head
  const int s    = (b >> 3) & 15;          // pair index 0..15
  const int role = b >> 7;                 // 0 = A, 1 = B
  const int qtL  = 31 - s;
  const int tid  = threadIdx.x;
  const int w    = tid >> 6;               // 0..7: head (w>>1), q-half (w&1)
  const int head = kvh * 4 + (w >> 1);
  const int lane = tid & 63;
  const int l31  = lane & 31, hi = lane >> 5;

  const u16* Kbase = QKV + 4096 + kvh * HD;           // + row*QKVST
  const u16* Vbase = VT + (size_t)kvh * HD * S_LEN;   // + vd*S_LEN + key

  auto stage = [&](int buf, int kt){
    const int k0 = kt * 64;
    #pragma unroll
    for (int pp = 0; pp < 2; pp++){
      int idx = pp * 512 + tid;            // K: row r(32) x chunk c(32)
      int r = idx >> 5, c = idx & 31;
      int cs = c ^ r;
      int key = r * 2 + (cs >> 4), d8 = (cs & 15) * 8;
      gload_lds16(Kbase + (size_t)(k0 + key) * QKVST + d8, &lds[buf][idx * 8]);
    }
    #pragma unroll
    for (int pp = 0; pp < 2; pp++){
      int idx = pp * 512 + tid;            // V: row r(32) x chunk c(32)
      int r = idx >> 5, c = idx & 31;
      int cs = c ^ r;
      int vd = r * 4 + (cs >> 3), k8 = (cs & 7) * 8;
      gload_lds16(Vbase + (size_t)vd * S_LEN + k0 + k8, &lds[2 + buf][idx * 8]);
    }
  };

  const float sb2 = sinkb[head] * LOG2E;
  bf16x8 qB[8];
  float m, Ll;
  f32x16 O[4];

  auto load_q = [&](int q0){
    const int qw = q0 + (w & 1) * 32;
    const u16* qrow = QKV + (size_t)(qw + l31) * QKVST + head * HD;
    #pragma unroll
    for (int t = 0; t < 8; t++) qB[t] = *(const bf16x8*)(qrow + t * 16 + hi * 8);
    #pragma unroll
    for (int n = 0; n < 4; n++) O[n] = f32x16{};
  };

  auto do_tile = [&](int cur, int k0, int qw){
    const u16* Kc = lds[cur];
    const u16* Vc = lds[2 + cur];
    f32x16 sc0 = {}, sc1 = {};
    const int krow0 = (l31 >> 1);
    const int kc0   = ((l31 & 1) << 4) | hi;
    __builtin_amdgcn_s_setprio(1);
    #pragma unroll
    for (int t = 0; t < 8; t++){
      bf16x8 ka0 = *(const bf16x8*)&Kc[krow0 * 256 + ((kc0 + 2 * t) ^ krow0) * 8];
      bf16x8 ka1 = *(const bf16x8*)&Kc[(16 + krow0) * 256 + ((kc0 + 2 * t) ^ (16 + krow0)) * 8];
      sc0 = __builtin_amdgcn_mfma_f32_32x32x16_bf16(ka0, qB[t], sc0, 0, 0, 0);
      sc1 = __builtin_amdgcn_mfma_f32_32x32x16_bf16(ka1, qB[t], sc1, 0, 0, 0);
    }
    __builtin_amdgcn_s_setprio(0);

    if (k0 + 63 > qw){
      const int qg = qw + l31;
      #pragma unroll
      for (int r = 0; r < 16; r++){
        int keyr = k0 + (r & 3) + 8 * (r >> 2) + 4 * hi;
        if (keyr      > qg) sc0[r] = -1e30f;
        if (keyr + 32 > qg) sc1[r] = -1e30f;
      }
    }
    float mx = sc0[0];
    #pragma unroll
    for (int r = 1; r < 16; r++) mx = fmaxf(mx, sc0[r]);
    #pragma unroll
    for (int r = 0; r < 16; r++) mx = fmaxf(mx, sc1[r]);
    mx = fmaxf(mx, __shfl_xor(mx, 32));
    if (!__all(mx <= m + RESCALE_THR2)){
      float mn = fmaxf(m, mx);
      float sf = exp2f(m - mn);
      m = mn;
      #pragma unroll
      for (int n = 0; n < 4; n++)
        #pragma unroll
        for (int r = 0; r < 16; r++) O[n][r] *= sf;
      Ll *= sf;
    }
    float p0[16], p1[16];
    #pragma unroll
    for (int r = 0; r < 16; r++){ p0[r] = exp2f(sc0[r] - m); Ll += p0[r]; }
    #pragma unroll
    for (int r = 0; r < 16; r++){ p1[r] = exp2f(sc1[r] - m); Ll += p1[r]; }

    __builtin_amdgcn_s_setprio(1);
    #pragma unroll
    for (int c = 0; c < 4; c++){
      const float* ps = (c & 2) ? p1 : p0;
      const int bb = (c & 1) * 8;
      u32 wa = cvtpk(ps[bb + 0], ps[bb + 1]);
      u32 wb = cvtpk(ps[bb + 2], ps[bb + 3]);
      u32 wc = cvtpk(ps[bb + 4], ps[bb + 5]);
      u32 wd = cvtpk(ps[bb + 6], ps[bb + 7]);
      asm("v_permlane32_swap_b32 %0, %1" : "+v"(wa), "+v"(wc));
      asm("v_permlane32_swap_b32 %0, %1" : "+v"(wb), "+v"(wd));
      u32x4 wv_; wv_[0] = wa; wv_[1] = wb; wv_[2] = wc; wv_[3] = wd;
      bf16x8 pf = __builtin_bit_cast(bf16x8, wv_);
      #pragma unroll
      for (int n = 0; n < 4; n++){
        const int vrow = n * 8 + (l31 >> 2);
        const int vcc  = ((l31 & 3) << 3) | (c << 1) | hi;
        bf16x8 va = *(const bf16x8*)&Vc[vrow * 256 + (vcc ^ vrow) * 8];
        O[n] = __builtin_amdgcn_mfma_f32_32x32x16_bf16(va, pf, O[n], 0, 0, 0);
      }
    }
    __builtin_amdgcn_s_setprio(0);
  };

  // run tiles [kt0, kt1) of stripe at q0; no-op (and no DMA) when empty
  auto run = [&](int q0, int kt0, int kt1){
    if (kt0 >= kt1) return;
    const int qw = q0 + (w & 1) * 32;
    stage(0, kt0);
    __syncthreads();
    int cur = 0;
    for (int kt = kt0; kt < kt1; kt++){
      if (kt + 1 < kt1) stage(cur ^ 1, kt + 1);
      if (kt * 64 < qw + 32) do_tile(cur, kt * 64, qw);
      __syncthreads();
      cur ^= 1;
    }
  };

  // epilogue: transpose O via the whole 64KB LDS (all buffers dead here).
  auto epilogue = [&](int q0, bool final_, int rec){
    float l = Ll + __shfl_xor(Ll, 32);
    float inv, lse;
    if (l > 0.f){ inv = 1.f / l; lse = m + __log2f(l); }
    else        { inv = 0.f;     lse = -1e30f; }
    u16* arena = &lds[0][0];               // 256 rows x 256B = 64KB
    const int rr = w * 32 + l31;
    #pragma unroll
    for (int n = 0; n < 4; n++)
      #pragma unroll
      for (int r = 0; r < 16; r++){
        int vd = n * 32 + (r & 3) + 8 * (r >> 2) + 4 * hi;
        int ch = (vd >> 3) ^ (l31 & 15);
        arena[rr * 128 + ch * 8 + (vd & 7)] = f2bf(O[n][r] * inv);
      }
    __syncthreads();
    if (final_){
      #pragma unroll
      for (int pp = 0; pp < 8; pp++){
        int idx = pp * 512 + tid;          // 4096 chunks: row(256) x c(16)
        int row = idx >> 4, c = idx & 15;
        u16x8 v = *(const u16x8*)&arena[row * 128 + ((c ^ (row & 15)) * 8)];
        *(u16x8*)&AO[(size_t)(q0 + (row & 63)) * AOST + (kvh * 4 + (row >> 6)) * HD + c * 8] = v;
      }
    } else {
      u16* base = PART + (size_t)((kvh * 16 + s) * 2 + rec) * PARTSZ;
      #pragma unroll
      for (int pp = 0; pp < 8; pp++){
        int idx = pp * 512 + tid;
        int row = idx >> 4, c = idx & 15;
        u16x8 v = *(const u16x8*)&arena[row * 128 + ((c ^ (row & 15)) * 8)];
        *(u16x8*)&base[row * 128 + c * 8] = v;
      }
      if (hi == 0) ((float*)(base + 32768))[rr] = lse;
    }
    __syncthreads();                       // arena reads done before next stage
  };

  const int q0L = qtL * 64;
  if (role == 0){
    load_q(q0L);
    m = sb2; Ll = (hi == 0) ? 1.f : 0.f;
    run(q0L, 0, 17);
    epilogue(q0L, false, 0);
  } else {
    load_q(q0L);
    m = -3.0e38f; Ll = 0.f;
    run(q0L, 17, 32 - s);
    epilogue(q0L, false, 1);
    const int q0S = s * 64;
    load_q(q0S);
    m = sb2; Ll = (hi == 0) ? 1.f : 0.f;
    run(q0S, 0, s + 1);
    epilogue(q0S, true, 0);
  }
}

// ---------------- merge partials: AO[long stripe] = lse-weighted combine ---
// 256 blocks (full CU fill): block = (record-pair, row-half).
__global__ void merge_kernel(const u16* __restrict__ PART, u16* __restrict__ AO){
  const int sidx = blockIdx.x >> 1;        // kvh*16 + s
  const int half = blockIdx.x & 1;         // rows [half*128, +128)
  const int kvh = sidx >> 4, s = sidx & 15;
  const int q0 = (31 - s) * 64;
  const u16* A = PART + (size_t)(sidx * 2 + 0) * PARTSZ;
  const u16* B = PART + (size_t)(sidx * 2 + 1) * PARTSZ;
  const float* lseA = (const float*)(A + 32768);
  const float* lseB = (const float*)(B + 32768);
  #pragma unroll
  for (int it = 0; it < 8; it++){
    int idx = (half * 8 + it) * 256 + threadIdx.x;   // chunks: row(256) x c(16)
    int row = idx >> 4, c = (idx & 15) * 8;
    float la = lseA[row], lb = lseB[row];
    float mx = fmaxf(la, lb);
    float wa = exp2f(la - mx), wb = exp2f(lb - mx);
    float inv = 1.f / (wa + wb);
    u16x8 va = *(const u16x8*)&A[row * 128 + c];
    u16x8 vb = *(const u16x8*)&B[row * 128 + c];
    u16x8 o;
    #pragma unroll
    for (int j = 0; j < 8; j++)
      o[j] = f2bf((bf2f(va[j]) * wa + bf2f(vb[j]) * wb) * inv);
    *(u16x8*)&AO[(size_t)(q0 + (row & 63)) * AOST + (kvh * 4 + (row >> 6)) * HD + c] = o;
  }
}

// ---------------- host-side launch ----------------
extern "C" void kernel_launch(void* const* d_in, const int* in_sizes, int n_in,
                              void* d_out, int out_size, void* d_ws, size_t ws_size,
                              hipStream_t stream){
  (void)in_sizes; (void)n_in; (void)out_size; (void)ws_size;
  const float* hs    = (const float*)d_in[0];
  const float* cosv  = (const float*)d_in[1];
  const float* sinv  = (const float*)d_in[2];
  /* d_in[3] attention_mask: pure causal triu(NEG,1) - implemented directly */
  const float* Wq    = (const float*)d_in[4];
  const float* Wk    = (const float*)d_in[5];
  const float* Wv    = (const float*)d_in[6];
  const float* Wo    = (const float*)d_in[7];
  const float* sinkb = (const float*)d_in[8];
  float* out = (float*)d_out;

  char* ws = (char*)d_ws;
  u16* XB    = (u16*)(ws);                  //  8,388,608  X bf16 [2048][2048]
  u16* WQKVB = (u16*)(ws + 8388608);        // 25,165,824  Wqkv bf16 [6144][2048]
  u16* WOB   = (u16*)(ws + 33554432);       // 16,777,216  Wo bf16 [2048][4096]
  u16* QKV   = (u16*)(ws + 50331648);       // 25,165,824  QKV bf16 [2048][6144]
  u16* VT    = (u16*)(ws + 75497472);       //  4,194,304  V^T bf16 [8][128][2048]
  u16* AO    = (u16*)(ws + 79691776);       // 16,777,216  attn out bf16 [2048][4096]
  u16* PART  = (u16*)(ws);                  // 17,039,360  partials (XB+WQKVB
                                            //   region, dead after QKV GEMM)

  cvt_all_kernel<<<12288, 256, 0, stream>>>((const f32x4*)hs, (const f32x4*)Wq,
                                            (const f32x4*)Wk, (const f32x4*)Wv,
                                            (const f32x4*)Wo, (u16x8*)ws);

  // fused QKV projection + RoPE + Q-scale(log2e): m97 geometry (128/128/32)
  gemm_bt_kernel<1, 1, 128, 128, 32><<<dim3(48, 16), 256, 0, stream>>>(XB, WQKVB, QKV, 2048, 6144, 2048, cosv, sinv);

  vtrans_kernel<<<8192, 256, 0, stream>>>(QKV, VT);

  // attention: 256 blocks x 512 threads (8-wave GQA-shared, stream-K 17/16)
  attn_kernel<<<dim3(256), 512, 0, stream>>>(QKV, VT, sinkb, AO, PART);

  // merge split (long) stripes: 256 blocks, lse-weighted combine
  merge_kernel<<<dim3(256), 256, 0, stream>>>(PART, AO);

  // output projection (f32 out): 128/64/64, 16 MFMA/barrier
  gemm_bt_kernel<0, 0, 128, 64, 64><<<dim3(32, 16), 256, 0, stream>>>(AO, WOB, out, 2048, 2048, 4096, nullptr, nullptr);
}